// Round 1
// baseline (1247.749 us; speedup 1.0000x reference)
//
#include <hip/hip_runtime.h>
#include <hip/hip_bf16.h>

// ---------------- problem constants ----------------
#define NN 20000      // nodes
#define EE 640000     // edges
#define RR 65         // relations
#define FIN1 128      // input feat
#define HH1 64        // hidden1
#define HH2 32        // hidden2
#define BB 8192       // pairs

constexpr int BM = 128;                 // edge-tile rows per GEMM block
constexpr int MAXT = EE / BM + RR;      // 5065 upper bound on tiles per sort

typedef __attribute__((ext_vector_type(8))) short short8;   // 8 bf16 (4 VGPRs) MFMA frag
typedef __attribute__((ext_vector_type(4))) float floatx4;  // 4 fp32 acc

// ---------------- workspace layout (bytes) ----------------
constexpr size_t aln(size_t x) { return (x + 255) & ~(size_t)255; }
constexpr size_t RN = (size_t)RR * NN;  // 1,300,000

constexpr size_t OFF_HIST0 = 0;                       // 65 int
constexpr size_t OFF_HIST1 = OFF_HIST0 + 65 * 4;
constexpr size_t OFF_CUR0  = OFF_HIST1 + 65 * 4;
constexpr size_t OFF_CUR1  = OFF_CUR0 + 65 * 4;
constexpr size_t OFF_CSUM  = OFF_CUR1 + 65 * 4;       // 32 float
constexpr size_t ZERO_BYTES = OFF_CSUM + 32 * 4;      // memset [0, ZERO_BYTES)
constexpr size_t OFF_OFF0  = aln(ZERO_BYTES);         // 66 int bucket offsets
constexpr size_t OFF_OFF1  = OFF_OFF0 + 66 * 4;
constexpr size_t OFF_TOFF0 = OFF_OFF1 + 66 * 4;       // 66 int tile offsets
constexpr size_t OFF_TOFF1 = OFF_TOFF0 + 66 * 4;
constexpr size_t OFF_T2R0  = aln(OFF_TOFF1 + 66 * 4); // MAXT int tile->relation
constexpr size_t OFF_T2R1  = OFF_T2R0 + (size_t)MAXT * 4;
constexpr size_t OFF_CNT0  = aln(OFF_T2R1 + (size_t)MAXT * 4);  // RN float
constexpr size_t OFF_CNT1  = OFF_CNT0 + RN * 4;                 // RN float
// bf16 node features alias the cnt arrays (cnt dead after k_fill; 5.12MB <= 5.2MB)
constexpr size_t OFF_XOB   = OFF_CNT0;
constexpr size_t OFF_XAB   = OFF_CNT1;
constexpr size_t OFF_W0    = aln(OFF_CNT1 + RN * 4);  // E float edge weights (e_type)
constexpr size_t OFF_W1    = OFF_W0 + (size_t)EE * 4; // E float (e_type1)
constexpr size_t OFF_PERM0 = OFF_W1 + (size_t)EE * 4; // E int
constexpr size_t OFF_PERM1 = OFF_PERM0 + (size_t)EE * 4;
constexpr size_t OFF_H1    = OFF_PERM1 + (size_t)EE * 4;        // 3 * N*64 float
constexpr size_t OFF_H1B   = OFF_H1 + (size_t)3 * NN * HH1 * 4; // 3 * N*64 bf16
constexpr size_t OFF_X2A   = OFF_H1B + (size_t)3 * NN * HH1 * 2; // N*32 float
constexpr size_t OFF_X2AA  = OFF_X2A + (size_t)NN * HH2 * 4;
constexpr size_t OFF_W1BT  = OFF_X2AA + (size_t)NN * HH2 * 4;   // R*64*128 bf16 (transposed)
constexpr size_t OFF_W2BT  = OFF_W1BT + (size_t)RR * HH1 * FIN1 * 2; // R*32*64 bf16
constexpr size_t WS_END    = OFF_W2BT + (size_t)RR * HH2 * HH1 * 2;  // ~50 MB

// output offsets (floats)
constexpr size_t O_LOG  = 0;
constexpr size_t O_ROS  = (size_t)BB * RR;          // 532480
constexpr size_t O_ROSA = O_ROS + (size_t)NN * 2;   // 572480
constexpr size_t O_X2O  = O_ROSA + (size_t)NN * 2;  // 612480

__device__ inline unsigned short f2bf(float f) {
    __hip_bfloat16 h = __float2bfloat16(f);
    return *reinterpret_cast<unsigned short*>(&h);
}

// ---------------- preprocessing ----------------
// per-(relation,dst) counts + per-relation histograms (block-local LDS hist to avoid contention)
__global__ void k_count(const int* __restrict__ ei, const int* __restrict__ et0,
                        const int* __restrict__ et1, float* cnt0, float* cnt1,
                        int* hist0, int* hist1) {
    __shared__ int lh0[RR], lh1[RR];
    int t = threadIdx.x;
    if (t < RR) { lh0[t] = 0; lh1[t] = 0; }
    __syncthreads();
    int e = blockIdx.x * 256 + t;
    if (e < EE) {
        int d = ei[EE + e];
        int r0 = et0[e], r1 = et1[e];
        atomicAdd(&lh0[r0], 1);
        atomicAdd(&lh1[r1], 1);
        unsafeAtomicAdd(&cnt0[r0 * NN + d], 1.0f);
        unsafeAtomicAdd(&cnt1[r1 * NN + d], 1.0f);
    }
    __syncthreads();
    if (t < RR) {
        if (lh0[t]) atomicAdd(&hist0[t], lh0[t]);
        if (lh1[t]) atomicAdd(&hist1[t], lh1[t]);
    }
}

// bucket offsets, tile offsets, tile->relation maps (single block, scans in LDS)
__global__ void k_scan(const int* __restrict__ hist0, const int* __restrict__ hist1,
                       int* off0, int* off1, int* toff0, int* toff1,
                       int* t2r0, int* t2r1) {
    __shared__ int h[2][RR];
    __shared__ int o[2][RR + 1], to[2][RR + 1];
    int t = threadIdx.x;
    if (t < RR) { h[0][t] = hist0[t]; h[1][t] = hist1[t]; }
    __syncthreads();
    if (t == 0) {
        for (int s = 0; s < 2; s++) {
            int a = 0, b = 0;
            for (int r = 0; r < RR; r++) {
                o[s][r] = a; to[s][r] = b;
                a += h[s][r]; b += (h[s][r] + BM - 1) / BM;
            }
            o[s][RR] = a; to[s][RR] = b;
        }
    }
    __syncthreads();
    if (t <= RR) { off0[t] = o[0][t]; off1[t] = o[1][t]; toff0[t] = to[0][t]; toff1[t] = to[1][t]; }
    for (int i = t; i < MAXT; i += blockDim.x) {
        for (int s = 0; s < 2; s++) {
            int total = to[s][RR];
            int r = -1;
            if (i < total) {
                int lo = 0, hi = RR;
                while (hi - lo > 1) { int mid = (lo + hi) >> 1; if (to[s][mid] <= i) lo = mid; else hi = mid; }
                r = lo;
            }
            (s ? t2r1 : t2r0)[i] = r;
        }
    }
}

// scatter edges into relation-sorted perm arrays; per-edge inverse-degree weights
__global__ void k_fill(const int* __restrict__ ei, const int* __restrict__ et0,
                       const int* __restrict__ et1,
                       const float* __restrict__ cnt0, const float* __restrict__ cnt1,
                       const int* __restrict__ off0, const int* __restrict__ off1,
                       int* cur0, int* cur1, int* perm0, int* perm1,
                       float* w0, float* w1) {
    __shared__ int lh[2][RR];
    __shared__ int lbase[2][RR];
    int t = threadIdx.x;
    if (t < RR) { lh[0][t] = 0; lh[1][t] = 0; }
    __syncthreads();
    int e = blockIdx.x * 256 + t;
    int r0 = 0, r1 = 0, p0 = 0, p1 = 0, d = 0;
    bool v = e < EE;
    if (v) {
        d = ei[EE + e];
        r0 = et0[e]; r1 = et1[e];
        p0 = atomicAdd(&lh[0][r0], 1);
        p1 = atomicAdd(&lh[1][r1], 1);
    }
    __syncthreads();
    if (t < RR) {
        lbase[0][t] = lh[0][t] ? atomicAdd(&cur0[t], lh[0][t]) : 0;
        lbase[1][t] = lh[1][t] ? atomicAdd(&cur1[t], lh[1][t]) : 0;
    }
    __syncthreads();
    if (v) {
        perm0[off0[r0] + lbase[0][r0] + p0] = e;
        perm1[off1[r1] + lbase[1][r1] + p1] = e;
        w0[e] = 1.0f / cnt0[r0 * NN + d];
        w1[e] = 1.0f / cnt1[r1 * NN + d];
    }
}

// bf16 conversions: node features (straight) and weights (transposed to [R][H][F])
__global__ void k_convert(const float* __restrict__ x_o, const float* __restrict__ x_a,
                          const float* __restrict__ W1, const float* __restrict__ W2,
                          unsigned short* xob, unsigned short* xab,
                          unsigned short* w1t, unsigned short* w2t) {
    int stride = gridDim.x * 256;
    int i0 = blockIdx.x * 256 + threadIdx.x;
    const int NX = NN * FIN1;
    for (int i = i0; i < NX; i += stride) { xob[i] = f2bf(x_o[i]); xab[i] = f2bf(x_a[i]); }
    const int NW1 = RR * HH1 * FIN1;
    for (int i = i0; i < NW1; i += stride) {
        int k = i % FIN1; int rh = i / FIN1; int hh = rh % HH1; int r = rh / HH1;
        w1t[i] = f2bf(W1[((size_t)r * FIN1 + k) * HH1 + hh]);
    }
    const int NW2 = RR * HH2 * HH1;
    for (int i = i0; i < NW2; i += stride) {
        int k = i % HH1; int rh = i / HH1; int hh = rh % HH2; int r = rh / HH2;
        w2t[i] = f2bf(W2[((size_t)r * HH1 + k) * HH2 + hh]);
    }
}

// root term: out[n,h] = x[n,:]@root[:,h] + b[h]   (fp32, full precision)
template <int FIN, int HOUT>
__global__ void k_base(const float* __restrict__ x0, const float* __restrict__ x1,
                       const float* __restrict__ x2,
                       const float* __restrict__ root, const float* __restrict__ bias,
                       float* o0, float* o1, float* o2) {
    const float* x = blockIdx.y == 0 ? x0 : (blockIdx.y == 1 ? x1 : x2);
    float* o = blockIdx.y == 0 ? o0 : (blockIdx.y == 1 ? o1 : o2);
    int lane = threadIdx.x % HOUT;
    int sub = threadIdx.x / HOUT;
    int n = blockIdx.x * (256 / HOUT) + sub;
    if (n >= NN) return;
    const float4* xr = (const float4*)(x + (size_t)n * FIN);
    float acc = bias[lane];
    #pragma unroll 4
    for (int f4 = 0; f4 < FIN / 4; f4++) {
        float4 xv = xr[f4];
        int f = f4 * 4;
        acc += xv.x * root[(f + 0) * HOUT + lane];
        acc += xv.y * root[(f + 1) * HOUT + lane];
        acc += xv.z * root[(f + 2) * HOUT + lane];
        acc += xv.w * root[(f + 3) * HOUT + lane];
    }
    o[(size_t)n * HOUT + lane] = acc;
}

// relation-grouped gather-GEMM with MFMA; epilogue scatters w_e * msg into out[dst]
template <int FIN, int HOUT>
__launch_bounds__(256, (FIN == 128 ? 3 : 4))
__global__ void k_gemm(const unsigned short* __restrict__ X0, const unsigned short* __restrict__ X1,
                       const unsigned short* __restrict__ X2,
                       float* O0, float* O1, float* O2,
                       const int* __restrict__ perm0, const int* __restrict__ perm1,
                       const int* __restrict__ off0, const int* __restrict__ off1,
                       const int* __restrict__ toff0, const int* __restrict__ toff1,
                       const int* __restrict__ t2r0, const int* __restrict__ t2r1,
                       const float* __restrict__ w0, const float* __restrict__ w1,
                       const unsigned short* __restrict__ WT,  // [R][HOUT][FIN] bf16
                       const int* __restrict__ ei) {
    const int enc = blockIdx.y;
    const unsigned short* X = enc == 0 ? X0 : enc == 1 ? X1 : X2;
    float* O = enc == 0 ? O0 : enc == 1 ? O1 : O2;
    const int* perm = enc == 2 ? perm1 : perm0;
    const int* off  = enc == 2 ? off1 : off0;
    const int* toff = enc == 2 ? toff1 : toff0;
    const int* t2r  = enc == 2 ? t2r1 : t2r0;
    const float* w  = enc == 2 ? w1 : w0;

    int b = blockIdx.x;
    int r = t2r[b];
    if (r < 0) return;
    int t = b - toff[r];
    int ebase = off[r] + t * BM;
    int mcount = min(BM, off[r + 1] - ebase);

    constexpr int LDK = FIN + 8;  // +8 bf16 pad: keeps 16B align, spreads banks
    __shared__ unsigned short As[BM][LDK];
    __shared__ unsigned short Bs[HOUT][LDK];
    __shared__ int Dd[BM];
    __shared__ float Ww[BM];
    __shared__ int Sr[BM];

    int tid = threadIdx.x;
    if (tid < BM) {
        int i = tid;
        if (i < mcount) {
            int e = perm[ebase + i];
            Sr[i] = ei[e];
            Dd[i] = ei[EE + e];
            Ww[i] = w[e];
        } else { Sr[i] = -1; Dd[i] = 0; Ww[i] = 0.f; }
    }
    __syncthreads();

    // stage B (W[r] transposed rows, 16B chunks)
    {
        const unsigned short* Wr = WT + (size_t)r * HOUT * FIN;
        constexpr int CHB = HOUT * FIN / 8;
        for (int c = tid; c < CHB; c += 256) {
            int row = c / (FIN / 8), cc = c % (FIN / 8);
            *(uint4*)&Bs[row][cc * 8] = *(const uint4*)&Wr[row * FIN + cc * 8];
        }
    }
    // stage A (gathered node rows)
    {
        constexpr int CHA = BM * FIN / 8;
        for (int c = tid; c < CHA; c += 256) {
            int row = c / (FIN / 8), cc = c % (FIN / 8);
            int s = Sr[row];
            uint4 v = {0u, 0u, 0u, 0u};
            if (s >= 0) v = *(const uint4*)&X[(size_t)s * FIN + cc * 8];
            *(uint4*)&As[row][cc * 8] = v;
        }
    }
    __syncthreads();

    const int wave = tid >> 6;      // 4 waves; each: 32 edges x HOUT
    const int lane = tid & 63;
    const int q = lane >> 4;
    const int ln = lane & 15;
    constexpr int NT = HOUT / 16;
    constexpr int KS = FIN / 32;
    const int mbase = wave * 32;

    floatx4 acc[2][NT];
    #pragma unroll
    for (int a = 0; a < 2; a++)
        #pragma unroll
        for (int nt = 0; nt < NT; nt++) acc[a][nt] = floatx4{0.f, 0.f, 0.f, 0.f};

    for (int ks = 0; ks < KS; ks++) {
        int kk = ks * 32 + q * 8;
        short8 af0 = *(const short8*)&As[mbase + ln][kk];
        short8 af1 = *(const short8*)&As[mbase + 16 + ln][kk];
        #pragma unroll
        for (int nt = 0; nt < NT; nt++) {
            short8 bf = *(const short8*)&Bs[nt * 16 + ln][kk];
            acc[0][nt] = __builtin_amdgcn_mfma_f32_16x16x32_bf16(af0, bf, acc[0][nt], 0, 0, 0);
            acc[1][nt] = __builtin_amdgcn_mfma_f32_16x16x32_bf16(af1, bf, acc[1][nt], 0, 0, 0);
        }
    }

    // epilogue: out[dst, h] += w_e * msg  (C/D layout: col=lane&15, row=quad*4+reg)
    #pragma unroll
    for (int mt = 0; mt < 2; mt++) {
        #pragma unroll
        for (int rr2 = 0; rr2 < 4; rr2++) {
            int i = mbase + mt * 16 + q * 4 + rr2;
            bool valid = (i < mcount);
            int dstn = Dd[i];
            float wt = Ww[i];
            #pragma unroll
            for (int nt = 0; nt < NT; nt++) {
                if (valid) {
                    float vv = wt * acc[mt][nt][rr2];
                    unsafeAtomicAdd(&O[(size_t)dstn * HOUT + nt * 16 + ln], vv);
                }
            }
        }
    }
}

// relu in place + bf16 copy (3 contiguous h1 buffers)
__global__ void k_relu_cvt(float* h1, unsigned short* h1b) {
    int i = blockIdx.x * 256 + threadIdx.x;
    if (i < 3 * NN * HH1) {
        float v = fmaxf(h1[i], 0.f);
        h1[i] = v;
        h1b[i] = f2bf(v);
    }
}

// column sums of x2_o -> csum[32]
__global__ void k_mean(const float* __restrict__ x2o, float* csum) {
    __shared__ float s[256];
    int t = threadIdx.x; int hh = t & 31; int g = t >> 5;
    float acc = 0.f;
    for (int n = blockIdx.x * 8 + g; n < NN; n += gridDim.x * 8)
        acc += x2o[(size_t)n * 32 + hh];
    s[t] = acc;
    __syncthreads();
    if (t < 32) {
        float v = 0.f;
        for (int gg = 0; gg < 8; gg++) v += s[gg * 32 + t];
        unsafeAtomicAdd(&csum[t], v);
    }
}

// c = sigmoid(csum/N); v = disc_W @ c; bilinear scores
__global__ void k_disc(const float* __restrict__ x2o, const float* __restrict__ x2a,
                       const float* __restrict__ x2aa, const float* __restrict__ csum,
                       const float* __restrict__ discW, const float* __restrict__ discb,
                       float* ret_os, float* ret_osa) {
    __shared__ float c[32], v[32];
    int t = threadIdx.x;
    if (t < 32) c[t] = 1.f / (1.f + expf(-csum[t] * (1.f / NN)));
    __syncthreads();
    if (t < 32) {
        float a = 0.f;
        for (int j = 0; j < 32; j++) a += discW[t * 32 + j] * c[j];
        v[t] = a;
    }
    __syncthreads();
    float db = discb[0];
    int n = blockIdx.x * 256 + t;
    if (n < NN) {
        float s1 = 0.f, s2 = 0.f, s3 = 0.f;
        for (int j = 0; j < 32; j++) {
            float vj = v[j];
            s1 += x2o[(size_t)n * 32 + j] * vj;
            s2 += x2a[(size_t)n * 32 + j] * vj;
            s3 += x2aa[(size_t)n * 32 + j] * vj;
        }
        ret_os[n * 2] = s1 + db;  ret_os[n * 2 + 1] = s2 + db;
        ret_osa[n * 2] = s1 + db; ret_osa[n * 2 + 1] = s3 + db;
    }
}

// pair classifier: e(448) @ cls_W(448x65) + cls_b; 8 pairs per block staged in LDS
__global__ void k_cls(const float* __restrict__ h1o, const float* __restrict__ x2o,
                      const float* __restrict__ feat, const float* __restrict__ attt,
                      const int* __restrict__ idx, const float* __restrict__ clsW,
                      const float* __restrict__ clsb, float* __restrict__ log_out) {
    __shared__ float ev[8][448];
    int t = threadIdx.x;
    int b0 = blockIdx.x * 8;
    float a0 = attt[0], a1 = attt[1];
    for (int x = t; x < 8 * 448; x += 256) {
        int bb = x / 448, j = x % 448;
        int pair = b0 + bb;
        int hseg = j / 224;
        int jj = j % 224;
        int node = idx[hseg * BB + pair];
        float val;
        if (jj < 64) val = a0 * h1o[(size_t)node * 64 + jj];
        else if (jj < 96) val = a1 * x2o[(size_t)node * 32 + (jj - 64)];
        else val = feat[(size_t)node * 128 + (jj - 96)];
        ev[bb][j] = val;
    }
    __syncthreads();
    for (int o = t; o < 8 * RR; o += 256) {
        int bb = o / RR, r = o % RR;
        const float* e = ev[bb];
        float acc = clsb[r];
        #pragma unroll 8
        for (int f = 0; f < 448; f++) acc += e[f] * clsW[f * RR + r];
        log_out[(size_t)(b0 + bb) * RR + r] = acc;
    }
}

extern "C" void kernel_launch(void* const* d_in, const int* in_sizes, int n_in,
                              void* d_out, int out_size, void* d_ws, size_t ws_size,
                              hipStream_t stream) {
    const float* x_o   = (const float*)d_in[0];
    const float* x_a   = (const float*)d_in[1];
    const float* feat  = (const float*)d_in[2];
    const float* W1    = (const float*)d_in[3];
    const float* root1 = (const float*)d_in[4];
    const float* b1    = (const float*)d_in[5];
    const float* W2    = (const float*)d_in[6];
    const float* root2 = (const float*)d_in[7];
    const float* b2    = (const float*)d_in[8];
    const float* attt  = (const float*)d_in[9];
    const float* discW = (const float*)d_in[10];
    const float* discb = (const float*)d_in[11];
    const float* clsW  = (const float*)d_in[12];
    const float* clsb  = (const float*)d_in[13];
    const int* ei      = (const int*)d_in[14];
    const int* et0     = (const int*)d_in[15];
    const int* et1     = (const int*)d_in[16];
    const int* idx     = (const int*)d_in[17];

    char* ws = (char*)d_ws;
    int* hist0 = (int*)(ws + OFF_HIST0);
    int* hist1 = (int*)(ws + OFF_HIST1);
    int* cur0  = (int*)(ws + OFF_CUR0);
    int* cur1  = (int*)(ws + OFF_CUR1);
    float* csum = (float*)(ws + OFF_CSUM);
    int* off0  = (int*)(ws + OFF_OFF0);
    int* off1  = (int*)(ws + OFF_OFF1);
    int* toff0 = (int*)(ws + OFF_TOFF0);
    int* toff1 = (int*)(ws + OFF_TOFF1);
    int* t2r0  = (int*)(ws + OFF_T2R0);
    int* t2r1  = (int*)(ws + OFF_T2R1);
    float* cnt0 = (float*)(ws + OFF_CNT0);
    float* cnt1 = (float*)(ws + OFF_CNT1);
    unsigned short* xob = (unsigned short*)(ws + OFF_XOB);
    unsigned short* xab = (unsigned short*)(ws + OFF_XAB);
    float* w0 = (float*)(ws + OFF_W0);
    float* w1 = (float*)(ws + OFF_W1);
    int* perm0 = (int*)(ws + OFF_PERM0);
    int* perm1 = (int*)(ws + OFF_PERM1);
    float* h1o  = (float*)(ws + OFF_H1);
    float* h1a  = h1o + (size_t)NN * HH1;
    float* h1aa = h1a + (size_t)NN * HH1;
    unsigned short* h1bo  = (unsigned short*)(ws + OFF_H1B);
    unsigned short* h1ba  = h1bo + (size_t)NN * HH1;
    unsigned short* h1baa = h1ba + (size_t)NN * HH1;
    float* x2a  = (float*)(ws + OFF_X2A);
    float* x2aa = (float*)(ws + OFF_X2AA);
    unsigned short* w1t = (unsigned short*)(ws + OFF_W1BT);
    unsigned short* w2t = (unsigned short*)(ws + OFF_W2BT);

    float* out = (float*)d_out;
    float* log_out = out + O_LOG;
    float* ret_os  = out + O_ROS;
    float* ret_osa = out + O_ROSA;
    float* x2o     = out + O_X2O;

    // 1) zero control block + count arrays
    hipMemsetAsync(ws, 0, ZERO_BYTES, stream);
    hipMemsetAsync(ws + OFF_CNT0, 0, 2 * RN * 4, stream);

    // 2) preprocessing
    k_count<<<2500, 256, 0, stream>>>(ei, et0, et1, cnt0, cnt1, hist0, hist1);
    k_scan<<<1, 128, 0, stream>>>(hist0, hist1, off0, off1, toff0, toff1, t2r0, t2r1);
    k_fill<<<2500, 256, 0, stream>>>(ei, et0, et1, cnt0, cnt1, off0, off1,
                                     cur0, cur1, perm0, perm1, w0, w1);
    k_convert<<<4096, 256, 0, stream>>>(x_o, x_a, W1, W2, xob, xab, w1t, w2t);

    // 3) layer 1: base + edge GEMM + relu/cvt
    dim3 gb1(5000, 3);
    k_base<FIN1, HH1><<<gb1, 256, 0, stream>>>(x_o, x_a, x_o, root1, b1, h1o, h1a, h1aa);
    dim3 gg(MAXT, 3);
    k_gemm<FIN1, HH1><<<gg, 256, 0, stream>>>(xob, xab, xob, h1o, h1a, h1aa,
                                              perm0, perm1, off0, off1, toff0, toff1,
                                              t2r0, t2r1, w0, w1, w1t, ei);
    k_relu_cvt<<<(3 * NN * HH1 + 255) / 256, 256, 0, stream>>>(h1o, h1bo);

    // 4) layer 2: base + edge GEMM
    dim3 gb2(2500, 3);
    k_base<HH1, HH2><<<gb2, 256, 0, stream>>>(h1o, h1a, h1aa, root2, b2, x2o, x2a, x2aa);
    k_gemm<HH1, HH2><<<gg, 256, 0, stream>>>(h1bo, h1ba, h1baa, x2o, x2a, x2aa,
                                             perm0, perm1, off0, off1, toff0, toff1,
                                             t2r0, t2r1, w0, w1, w2t, ei);

    // 5) readout + discriminator + classifier
    k_mean<<<256, 256, 0, stream>>>(x2o, csum);
    k_disc<<<(NN + 255) / 256, 256, 0, stream>>>(x2o, x2a, x2aa, csum, discW, discb,
                                                 ret_os, ret_osa);
    k_cls<<<BB / 8, 256, 0, stream>>>(h1o, x2o, feat, attt, idx, clsW, clsb, log_out);
}

// Round 2
// 1136.882 us; speedup vs baseline: 1.0975x; 1.0975x over previous
//
#include <hip/hip_runtime.h>
#include <hip/hip_bf16.h>

// ---------------- problem constants ----------------
#define NN 20000      // nodes
#define EE 640000     // edges
#define RR 65         // relations
#define FIN1 128      // input feat
#define HH1 64        // hidden1
#define HH2 32        // hidden2
#define BB 8192       // pairs

constexpr int BM = 128;                 // edge-tile rows per GEMM block
constexpr int MAXT = EE / BM + RR;      // 5065 upper bound on tiles per sort

typedef __attribute__((ext_vector_type(8))) short short8;   // 8 bf16 (4 VGPRs) MFMA frag
typedef __attribute__((ext_vector_type(4))) float floatx4;  // 4 fp32 acc

// ---------------- workspace layout (bytes) ----------------
constexpr size_t aln(size_t x) { return (x + 255) & ~(size_t)255; }
constexpr size_t RN = (size_t)RR * NN;  // 1,300,000

constexpr size_t OFF_HIST0 = 0;                       // 65 int
constexpr size_t OFF_HIST1 = OFF_HIST0 + 65 * 4;
constexpr size_t OFF_CUR0  = OFF_HIST1 + 65 * 4;
constexpr size_t OFF_CUR1  = OFF_CUR0 + 65 * 4;
constexpr size_t OFF_CSUM  = OFF_CUR1 + 65 * 4;       // 32 float
constexpr size_t OFF_CNTD  = aln(OFF_CSUM + 32 * 4);  // 20000 int (per-dst degree)
constexpr size_t OFF_CURD  = OFF_CNTD + (size_t)NN * 4;
constexpr size_t ZERO_BYTES = OFF_CURD + (size_t)NN * 4;   // memset [0, ZERO_BYTES)
constexpr size_t OFF_DSTOFF = aln(ZERO_BYTES);        // 20001 int dst CSR offsets
constexpr size_t OFF_OFF0  = aln(OFF_DSTOFF + ((size_t)NN + 1) * 4); // 66 int bucket offsets
constexpr size_t OFF_OFF1  = OFF_OFF0 + 66 * 4;
constexpr size_t OFF_TOFF0 = OFF_OFF1 + 66 * 4;       // 66 int tile offsets
constexpr size_t OFF_TOFF1 = OFF_TOFF0 + 66 * 4;
constexpr size_t OFF_T2R0  = aln(OFF_TOFF1 + 66 * 4); // MAXT int tile->relation
constexpr size_t OFF_T2R1  = OFF_T2R0 + (size_t)MAXT * 4;
constexpr size_t OFF_POSD  = aln(OFF_T2R1 + (size_t)MAXT * 4);  // E int (dst-sorted slot)
constexpr size_t OFF_CNT0  = aln(OFF_POSD + (size_t)EE * 4);    // RN float
constexpr size_t OFF_CNT1  = OFF_CNT0 + RN * 4;                 // RN float
// bf16 node features alias the cnt arrays (cnt dead after k_fill; 5.12MB <= 5.2MB)
constexpr size_t OFF_XOB   = OFF_CNT0;
constexpr size_t OFF_XAB   = OFF_CNT1;
constexpr size_t OFF_W0    = aln(OFF_CNT1 + RN * 4);  // E float edge weights (e_type)
constexpr size_t OFF_W1    = OFF_W0 + (size_t)EE * 4; // E float (e_type1)
constexpr size_t OFF_PERM0 = OFF_W1 + (size_t)EE * 4; // E int
constexpr size_t OFF_PERM1 = OFF_PERM0 + (size_t)EE * 4;
constexpr size_t OFF_H1    = OFF_PERM1 + (size_t)EE * 4;        // 3 * N*64 float
constexpr size_t OFF_H1B   = OFF_H1 + (size_t)3 * NN * HH1 * 4; // 3 * N*64 bf16
constexpr size_t OFF_X2A   = OFF_H1B + (size_t)3 * NN * HH1 * 2; // N*32 float
constexpr size_t OFF_X2AA  = OFF_X2A + (size_t)NN * HH2 * 4;
constexpr size_t OFF_W1BT  = OFF_X2AA + (size_t)NN * HH2 * 4;   // R*64*128 bf16 (transposed)
constexpr size_t OFF_W2BT  = OFF_W1BT + (size_t)RR * HH1 * FIN1 * 2; // R*32*64 bf16
constexpr size_t OFF_MSG   = aln(OFF_W2BT + (size_t)RR * HH2 * HH1 * 2); // E*64 bf16 (per-enc reuse)
constexpr size_t WS_END    = OFF_MSG + (size_t)EE * HH1 * 2;    // ~135 MB

// output offsets (floats)
constexpr size_t O_LOG  = 0;
constexpr size_t O_ROS  = (size_t)BB * RR;          // 532480
constexpr size_t O_ROSA = O_ROS + (size_t)NN * 2;   // 572480
constexpr size_t O_X2O  = O_ROSA + (size_t)NN * 2;  // 612480

__device__ inline unsigned short f2bf(float f) {
    __hip_bfloat16 h = __float2bfloat16(f);
    return *reinterpret_cast<unsigned short*>(&h);
}
__device__ inline float bfbits2f(unsigned int hi_bits) {   // bits already in [31:16]
    return __uint_as_float(hi_bits);
}

// ---------------- preprocessing ----------------
// per-(relation,dst) counts, per-dst degree, per-relation histograms
__global__ void k_count(const int* __restrict__ ei, const int* __restrict__ et0,
                        const int* __restrict__ et1, float* cnt0, float* cnt1,
                        int* hist0, int* hist1, int* cntD) {
    __shared__ int lh0[RR], lh1[RR];
    int t = threadIdx.x;
    if (t < RR) { lh0[t] = 0; lh1[t] = 0; }
    __syncthreads();
    int e = blockIdx.x * 256 + t;
    if (e < EE) {
        int d = ei[EE + e];
        int r0 = et0[e], r1 = et1[e];
        atomicAdd(&lh0[r0], 1);
        atomicAdd(&lh1[r1], 1);
        unsafeAtomicAdd(&cnt0[r0 * NN + d], 1.0f);
        unsafeAtomicAdd(&cnt1[r1 * NN + d], 1.0f);
        atomicAdd(&cntD[d], 1);
    }
    __syncthreads();
    if (t < RR) {
        if (lh0[t]) atomicAdd(&hist0[t], lh0[t]);
        if (lh1[t]) atomicAdd(&hist1[t], lh1[t]);
    }
}

// bucket offsets, tile offsets, tile->relation maps (single block)
__global__ void k_scan(const int* __restrict__ hist0, const int* __restrict__ hist1,
                       int* off0, int* off1, int* toff0, int* toff1,
                       int* t2r0, int* t2r1) {
    __shared__ int h[2][RR];
    __shared__ int o[2][RR + 1], to[2][RR + 1];
    int t = threadIdx.x;
    if (t < RR) { h[0][t] = hist0[t]; h[1][t] = hist1[t]; }
    __syncthreads();
    if (t == 0) {
        for (int s = 0; s < 2; s++) {
            int a = 0, b = 0;
            for (int r = 0; r < RR; r++) {
                o[s][r] = a; to[s][r] = b;
                a += h[s][r]; b += (h[s][r] + BM - 1) / BM;
            }
            o[s][RR] = a; to[s][RR] = b;
        }
    }
    __syncthreads();
    if (t <= RR) { off0[t] = o[0][t]; off1[t] = o[1][t]; toff0[t] = to[0][t]; toff1[t] = to[1][t]; }
    for (int i = t; i < MAXT; i += blockDim.x) {
        for (int s = 0; s < 2; s++) {
            int total = to[s][RR];
            int r = -1;
            if (i < total) {
                int lo = 0, hi = RR;
                while (hi - lo > 1) { int mid = (lo + hi) >> 1; if (to[s][mid] <= i) lo = mid; else hi = mid; }
                r = lo;
            }
            (s ? t2r1 : t2r0)[i] = r;
        }
    }
}

// exclusive scan of per-dst degrees -> dstOff[NN+1] (single block, 256 threads)
__global__ void k_scanD(const int* __restrict__ cntD, int* __restrict__ dstOff) {
    __shared__ int s[256];
    int t = threadIdx.x;
    constexpr int PER = (NN + 255) / 256;   // 79
    int lo = t * PER, hi = min(NN, lo + PER);
    int sum = 0;
    for (int i = lo; i < hi; i++) sum += cntD[i];
    s[t] = sum;
    __syncthreads();
    for (int ofs = 1; ofs < 256; ofs <<= 1) {
        int v = 0;
        if (t >= ofs) v = s[t - ofs];
        __syncthreads();
        if (t >= ofs) s[t] += v;
        __syncthreads();
    }
    int run = s[t] - sum;   // exclusive base
    for (int i = lo; i < hi; i++) { dstOff[i] = run; run += cntD[i]; }
    if (t == 255) dstOff[NN] = run;
}

// scatter edges into relation-sorted perm arrays; per-edge weights; dst-sorted slot
__global__ void k_fill(const int* __restrict__ ei, const int* __restrict__ et0,
                       const int* __restrict__ et1,
                       const float* __restrict__ cnt0, const float* __restrict__ cnt1,
                       const int* __restrict__ off0, const int* __restrict__ off1,
                       int* cur0, int* cur1, int* perm0, int* perm1,
                       float* w0, float* w1,
                       const int* __restrict__ dstOff, int* curD, int* posD) {
    __shared__ int lh[2][RR];
    __shared__ int lbase[2][RR];
    int t = threadIdx.x;
    if (t < RR) { lh[0][t] = 0; lh[1][t] = 0; }
    __syncthreads();
    int e = blockIdx.x * 256 + t;
    int r0 = 0, r1 = 0, p0 = 0, p1 = 0, d = 0;
    bool v = e < EE;
    if (v) {
        d = ei[EE + e];
        r0 = et0[e]; r1 = et1[e];
        p0 = atomicAdd(&lh[0][r0], 1);
        p1 = atomicAdd(&lh[1][r1], 1);
    }
    __syncthreads();
    if (t < RR) {
        lbase[0][t] = lh[0][t] ? atomicAdd(&cur0[t], lh[0][t]) : 0;
        lbase[1][t] = lh[1][t] ? atomicAdd(&cur1[t], lh[1][t]) : 0;
    }
    __syncthreads();
    if (v) {
        perm0[off0[r0] + lbase[0][r0] + p0] = e;
        perm1[off1[r1] + lbase[1][r1] + p1] = e;
        w0[e] = 1.0f / cnt0[r0 * NN + d];
        w1[e] = 1.0f / cnt1[r1 * NN + d];
        posD[e] = dstOff[d] + atomicAdd(&curD[d], 1);
    }
}

// bf16 conversions: node features (straight) and weights (transposed to [R][H][F])
__global__ void k_convert(const float* __restrict__ x_o, const float* __restrict__ x_a,
                          const float* __restrict__ W1, const float* __restrict__ W2,
                          unsigned short* xob, unsigned short* xab,
                          unsigned short* w1t, unsigned short* w2t) {
    int stride = gridDim.x * 256;
    int i0 = blockIdx.x * 256 + threadIdx.x;
    const int NX = NN * FIN1;
    for (int i = i0; i < NX; i += stride) { xob[i] = f2bf(x_o[i]); xab[i] = f2bf(x_a[i]); }
    const int NW1 = RR * HH1 * FIN1;
    for (int i = i0; i < NW1; i += stride) {
        int k = i % FIN1; int rh = i / FIN1; int hh = rh % HH1; int r = rh / HH1;
        w1t[i] = f2bf(W1[((size_t)r * FIN1 + k) * HH1 + hh]);
    }
    const int NW2 = RR * HH2 * HH1;
    for (int i = i0; i < NW2; i += stride) {
        int k = i % HH1; int rh = i / HH1; int hh = rh % HH2; int r = rh / HH2;
        w2t[i] = f2bf(W2[((size_t)r * HH1 + k) * HH2 + hh]);
    }
}

// root term: out[n,h] = x[n,:]@root[:,h] + b[h]   (fp32, full precision)
template <int FIN, int HOUT>
__global__ void k_base(const float* __restrict__ x0, const float* __restrict__ x1,
                       const float* __restrict__ x2,
                       const float* __restrict__ root, const float* __restrict__ bias,
                       float* o0, float* o1, float* o2) {
    const float* x = blockIdx.y == 0 ? x0 : (blockIdx.y == 1 ? x1 : x2);
    float* o = blockIdx.y == 0 ? o0 : (blockIdx.y == 1 ? o1 : o2);
    int lane = threadIdx.x % HOUT;
    int sub = threadIdx.x / HOUT;
    int n = blockIdx.x * (256 / HOUT) + sub;
    if (n >= NN) return;
    const float4* xr = (const float4*)(x + (size_t)n * FIN);
    float acc = bias[lane];
    #pragma unroll 4
    for (int f4 = 0; f4 < FIN / 4; f4++) {
        float4 xv = xr[f4];
        int f = f4 * 4;
        acc += xv.x * root[(f + 0) * HOUT + lane];
        acc += xv.y * root[(f + 1) * HOUT + lane];
        acc += xv.z * root[(f + 2) * HOUT + lane];
        acc += xv.w * root[(f + 3) * HOUT + lane];
    }
    o[(size_t)n * HOUT + lane] = acc;
}

// relation-grouped gather-GEMM with MFMA; epilogue writes weighted bf16 msg rows
// to dst-sorted slots (full-cacheline plain stores — no RMW atomics).
template <int FIN, int HOUT>
__launch_bounds__(256, (FIN == 128 ? 3 : 4))
__global__ void k_gemm(const unsigned short* __restrict__ X,
                       unsigned short* __restrict__ msg,
                       const int* __restrict__ perm, const int* __restrict__ off,
                       const int* __restrict__ toff, const int* __restrict__ t2r,
                       const float* __restrict__ w, const int* __restrict__ posD,
                       const unsigned short* __restrict__ WT,  // [R][HOUT][FIN] bf16
                       const int* __restrict__ ei) {
    int b = blockIdx.x;
    int r = t2r[b];
    if (r < 0) return;
    int t = b - toff[r];
    int ebase = off[r] + t * BM;
    int mcount = min(BM, off[r + 1] - ebase);

    constexpr int LDK = FIN + 8;  // +8 bf16 pad
    __shared__ unsigned short As[BM][LDK];
    __shared__ unsigned short Bs[HOUT][LDK];
    __shared__ int Sr[BM];
    __shared__ float Ww[BM];
    __shared__ int Pd[BM];

    int tid = threadIdx.x;
    if (tid < BM) {
        if (tid < mcount) {
            int e = perm[ebase + tid];
            Sr[tid] = ei[e];
            Ww[tid] = w[e];
            Pd[tid] = posD[e];
        } else { Sr[tid] = -1; Ww[tid] = 0.f; Pd[tid] = 0; }
    }
    __syncthreads();

    // stage B (W[r] transposed rows, 16B chunks)
    {
        const unsigned short* Wr = WT + (size_t)r * HOUT * FIN;
        constexpr int CHB = HOUT * FIN / 8;
        for (int c = tid; c < CHB; c += 256) {
            int row = c / (FIN / 8), cc = c % (FIN / 8);
            *(uint4*)&Bs[row][cc * 8] = *(const uint4*)&Wr[row * FIN + cc * 8];
        }
    }
    // stage A (gathered node rows)
    {
        constexpr int CHA = BM * FIN / 8;
        for (int c = tid; c < CHA; c += 256) {
            int row = c / (FIN / 8), cc = c % (FIN / 8);
            int s = Sr[row];
            uint4 v = {0u, 0u, 0u, 0u};
            if (s >= 0) v = *(const uint4*)&X[(size_t)s * FIN + cc * 8];
            *(uint4*)&As[row][cc * 8] = v;
        }
    }
    __syncthreads();

    const int wave = tid >> 6;      // 4 waves; each: 32 edges x HOUT
    const int lane = tid & 63;
    const int q = lane >> 4;
    const int ln = lane & 15;
    constexpr int NT = HOUT / 16;
    constexpr int KS = FIN / 32;
    const int mbase = wave * 32;

    floatx4 acc[2][NT];
    #pragma unroll
    for (int a = 0; a < 2; a++)
        #pragma unroll
        for (int nt = 0; nt < NT; nt++) acc[a][nt] = floatx4{0.f, 0.f, 0.f, 0.f};

    for (int ks = 0; ks < KS; ks++) {
        int kk = ks * 32 + q * 8;
        short8 af0 = *(const short8*)&As[mbase + ln][kk];
        short8 af1 = *(const short8*)&As[mbase + 16 + ln][kk];
        #pragma unroll
        for (int nt = 0; nt < NT; nt++) {
            short8 bf = *(const short8*)&Bs[nt * 16 + ln][kk];
            acc[0][nt] = __builtin_amdgcn_mfma_f32_16x16x32_bf16(af0, bf, acc[0][nt], 0, 0, 0);
            acc[1][nt] = __builtin_amdgcn_mfma_f32_16x16x32_bf16(af1, bf, acc[1][nt], 0, 0, 0);
        }
    }

    // epilogue: transpose weighted bf16 msgs through LDS (overlay As), then
    // coalesced full-line scatter to msg[posD[e]*HOUT .. +HOUT)
    __syncthreads();
    constexpr int LDM = HOUT + 8;   // pad to stagger banks; row stride %16B == 0
    unsigned short* Ms = &As[0][0];
    #pragma unroll
    for (int mt = 0; mt < 2; mt++) {
        #pragma unroll
        for (int rr2 = 0; rr2 < 4; rr2++) {
            int i = mbase + mt * 16 + q * 4 + rr2;
            float wt = Ww[i];
            #pragma unroll
            for (int nt = 0; nt < NT; nt++)
                Ms[i * LDM + nt * 16 + ln] = f2bf(wt * acc[mt][nt][rr2]);
        }
    }
    __syncthreads();
    constexpr int CH = HOUT / 8;    // 16B chunks per row
    for (int c = tid; c < BM * CH; c += 256) {
        int row = c / CH, cc = c % CH;
        if (row < mcount)
            *(uint4*)&msg[(size_t)Pd[row] * HOUT + cc * 8] = *(const uint4*)&Ms[row * LDM + cc * 8];
    }
}

// segment-sum msg rows per dst (contiguous in dst-sorted order), add root base,
// optional fused relu + bf16 cast. One wave per dst.
template <int H, bool RELU>
__global__ void k_reduce(const unsigned short* __restrict__ msg,
                         const int* __restrict__ dstOff,
                         float* __restrict__ base_io,
                         unsigned short* __restrict__ bfout) {
    int d = blockIdx.x * 4 + (threadIdx.x >> 6);
    if (d >= NN) return;
    int lane = threadIdx.x & 63;
    constexpr int HP = H / 2;          // col pairs per row
    constexpr int RPI = 64 / HP;       // rows per iteration (H=64 -> 2, H=32 -> 4)
    int sub = lane / HP;
    int cp = lane % HP;
    int j0 = dstOff[d], j1 = dstOff[d + 1];
    float a0 = 0.f, a1 = 0.f;
    for (int j = j0 + sub; j < j1; j += RPI) {
        unsigned int v = *(const unsigned int*)&msg[(size_t)j * H + cp * 2];
        a0 += bfbits2f(v << 16);
        a1 += bfbits2f(v & 0xffff0000u);
    }
    a0 += __shfl_down(a0, 32); a1 += __shfl_down(a1, 32);
    if (H == 32) { a0 += __shfl_down(a0, 16); a1 += __shfl_down(a1, 16); }
    if (lane < HP) {
        size_t o = (size_t)d * H + cp * 2;
        float v0 = base_io[o] + a0, v1 = base_io[o + 1] + a1;
        if (RELU) { v0 = fmaxf(v0, 0.f); v1 = fmaxf(v1, 0.f); }
        base_io[o] = v0; base_io[o + 1] = v1;
        if (RELU) { bfout[o] = f2bf(v0); bfout[o + 1] = f2bf(v1); }
    }
}

// column sums of x2_o -> csum[32]
__global__ void k_mean(const float* __restrict__ x2o, float* csum) {
    __shared__ float s[256];
    int t = threadIdx.x; int hh = t & 31; int g = t >> 5;
    float acc = 0.f;
    for (int n = blockIdx.x * 8 + g; n < NN; n += gridDim.x * 8)
        acc += x2o[(size_t)n * 32 + hh];
    s[t] = acc;
    __syncthreads();
    if (t < 32) {
        float v = 0.f;
        for (int gg = 0; gg < 8; gg++) v += s[gg * 32 + t];
        unsafeAtomicAdd(&csum[t], v);
    }
}

// c = sigmoid(csum/N); v = disc_W @ c; bilinear scores
__global__ void k_disc(const float* __restrict__ x2o, const float* __restrict__ x2a,
                       const float* __restrict__ x2aa, const float* __restrict__ csum,
                       const float* __restrict__ discW, const float* __restrict__ discb,
                       float* ret_os, float* ret_osa) {
    __shared__ float c[32], v[32];
    int t = threadIdx.x;
    if (t < 32) c[t] = 1.f / (1.f + expf(-csum[t] * (1.f / NN)));
    __syncthreads();
    if (t < 32) {
        float a = 0.f;
        for (int j = 0; j < 32; j++) a += discW[t * 32 + j] * c[j];
        v[t] = a;
    }
    __syncthreads();
    float db = discb[0];
    int n = blockIdx.x * 256 + t;
    if (n < NN) {
        float s1 = 0.f, s2 = 0.f, s3 = 0.f;
        for (int j = 0; j < 32; j++) {
            float vj = v[j];
            s1 += x2o[(size_t)n * 32 + j] * vj;
            s2 += x2a[(size_t)n * 32 + j] * vj;
            s3 += x2aa[(size_t)n * 32 + j] * vj;
        }
        ret_os[n * 2] = s1 + db;  ret_os[n * 2 + 1] = s2 + db;
        ret_osa[n * 2] = s1 + db; ret_osa[n * 2 + 1] = s3 + db;
    }
}

// pair classifier: e(448) @ cls_W(448x65) + cls_b; 8 pairs per block staged in LDS
__global__ void k_cls(const float* __restrict__ h1o, const float* __restrict__ x2o,
                      const float* __restrict__ feat, const float* __restrict__ attt,
                      const int* __restrict__ idx, const float* __restrict__ clsW,
                      const float* __restrict__ clsb, float* __restrict__ log_out) {
    __shared__ float ev[8][448];
    int t = threadIdx.x;
    int b0 = blockIdx.x * 8;
    float a0 = attt[0], a1 = attt[1];
    for (int x = t; x < 8 * 448; x += 256) {
        int bb = x / 448, j = x % 448;
        int pair = b0 + bb;
        int hseg = j / 224;
        int jj = j % 224;
        int node = idx[hseg * BB + pair];
        float val;
        if (jj < 64) val = a0 * h1o[(size_t)node * 64 + jj];
        else if (jj < 96) val = a1 * x2o[(size_t)node * 32 + (jj - 64)];
        else val = feat[(size_t)node * 128 + (jj - 96)];
        ev[bb][j] = val;
    }
    __syncthreads();
    for (int o = t; o < 8 * RR; o += 256) {
        int bb = o / RR, r = o % RR;
        const float* e = ev[bb];
        float acc = clsb[r];
        #pragma unroll 8
        for (int f = 0; f < 448; f++) acc += e[f] * clsW[f * RR + r];
        log_out[(size_t)(b0 + bb) * RR + r] = acc;
    }
}

extern "C" void kernel_launch(void* const* d_in, const int* in_sizes, int n_in,
                              void* d_out, int out_size, void* d_ws, size_t ws_size,
                              hipStream_t stream) {
    const float* x_o   = (const float*)d_in[0];
    const float* x_a   = (const float*)d_in[1];
    const float* feat  = (const float*)d_in[2];
    const float* W1    = (const float*)d_in[3];
    const float* root1 = (const float*)d_in[4];
    const float* b1    = (const float*)d_in[5];
    const float* W2    = (const float*)d_in[6];
    const float* root2 = (const float*)d_in[7];
    const float* b2    = (const float*)d_in[8];
    const float* attt  = (const float*)d_in[9];
    const float* discW = (const float*)d_in[10];
    const float* discb = (const float*)d_in[11];
    const float* clsW  = (const float*)d_in[12];
    const float* clsb  = (const float*)d_in[13];
    const int* ei      = (const int*)d_in[14];
    const int* et0     = (const int*)d_in[15];
    const int* et1     = (const int*)d_in[16];
    const int* idx     = (const int*)d_in[17];

    char* ws = (char*)d_ws;
    int* hist0 = (int*)(ws + OFF_HIST0);
    int* hist1 = (int*)(ws + OFF_HIST1);
    int* cur0  = (int*)(ws + OFF_CUR0);
    int* cur1  = (int*)(ws + OFF_CUR1);
    float* csum = (float*)(ws + OFF_CSUM);
    int* cntD  = (int*)(ws + OFF_CNTD);
    int* curD  = (int*)(ws + OFF_CURD);
    int* dstOff = (int*)(ws + OFF_DSTOFF);
    int* off0  = (int*)(ws + OFF_OFF0);
    int* off1  = (int*)(ws + OFF_OFF1);
    int* toff0 = (int*)(ws + OFF_TOFF0);
    int* toff1 = (int*)(ws + OFF_TOFF1);
    int* t2r0  = (int*)(ws + OFF_T2R0);
    int* t2r1  = (int*)(ws + OFF_T2R1);
    int* posD  = (int*)(ws + OFF_POSD);
    float* cnt0 = (float*)(ws + OFF_CNT0);
    float* cnt1 = (float*)(ws + OFF_CNT1);
    unsigned short* xob = (unsigned short*)(ws + OFF_XOB);
    unsigned short* xab = (unsigned short*)(ws + OFF_XAB);
    float* w0 = (float*)(ws + OFF_W0);
    float* w1 = (float*)(ws + OFF_W1);
    int* perm0 = (int*)(ws + OFF_PERM0);
    int* perm1 = (int*)(ws + OFF_PERM1);
    float* h1o  = (float*)(ws + OFF_H1);
    float* h1a  = h1o + (size_t)NN * HH1;
    float* h1aa = h1a + (size_t)NN * HH1;
    unsigned short* h1bo  = (unsigned short*)(ws + OFF_H1B);
    unsigned short* h1ba  = h1bo + (size_t)NN * HH1;
    unsigned short* h1baa = h1ba + (size_t)NN * HH1;
    float* x2a  = (float*)(ws + OFF_X2A);
    float* x2aa = (float*)(ws + OFF_X2AA);
    unsigned short* w1t = (unsigned short*)(ws + OFF_W1BT);
    unsigned short* w2t = (unsigned short*)(ws + OFF_W2BT);
    unsigned short* msg = (unsigned short*)(ws + OFF_MSG);

    float* out = (float*)d_out;
    float* log_out = out + O_LOG;
    float* ret_os  = out + O_ROS;
    float* ret_osa = out + O_ROSA;
    float* x2o     = out + O_X2O;

    // 1) zero control block + count arrays
    hipMemsetAsync(ws, 0, ZERO_BYTES, stream);
    hipMemsetAsync(ws + OFF_CNT0, 0, 2 * RN * 4, stream);

    // 2) preprocessing
    k_count<<<2500, 256, 0, stream>>>(ei, et0, et1, cnt0, cnt1, hist0, hist1, cntD);
    k_scan<<<1, 128, 0, stream>>>(hist0, hist1, off0, off1, toff0, toff1, t2r0, t2r1);
    k_scanD<<<1, 256, 0, stream>>>(cntD, dstOff);
    k_fill<<<2500, 256, 0, stream>>>(ei, et0, et1, cnt0, cnt1, off0, off1,
                                     cur0, cur1, perm0, perm1, w0, w1,
                                     dstOff, curD, posD);
    k_convert<<<4096, 256, 0, stream>>>(x_o, x_a, W1, W2, xob, xab, w1t, w2t);

    // 3) layer 1: base + per-encoding (edge GEMM -> dst reduce with fused relu/cvt)
    dim3 gb1(5000, 3);
    k_base<FIN1, HH1><<<gb1, 256, 0, stream>>>(x_o, x_a, x_o, root1, b1, h1o, h1a, h1aa);
    {
        const unsigned short* Xs[3] = {xob, xab, xob};
        float* Os[3] = {h1o, h1a, h1aa};
        unsigned short* Obs[3] = {h1bo, h1ba, h1baa};
        for (int enc = 0; enc < 3; enc++) {
            const int* perm = enc == 2 ? perm1 : perm0;
            const int* off  = enc == 2 ? off1 : off0;
            const int* toff = enc == 2 ? toff1 : toff0;
            const int* t2r  = enc == 2 ? t2r1 : t2r0;
            const float* w  = enc == 2 ? w1 : w0;
            k_gemm<FIN1, HH1><<<MAXT, 256, 0, stream>>>(Xs[enc], msg, perm, off, toff,
                                                        t2r, w, posD, w1t, ei);
            k_reduce<HH1, true><<<NN / 4, 256, 0, stream>>>(msg, dstOff, Os[enc], Obs[enc]);
        }
    }

    // 4) layer 2: base + per-encoding (edge GEMM -> dst reduce)
    dim3 gb2(2500, 3);
    k_base<HH1, HH2><<<gb2, 256, 0, stream>>>(h1o, h1a, h1aa, root2, b2, x2o, x2a, x2aa);
    {
        const unsigned short* Xs[3] = {h1bo, h1ba, h1baa};
        float* Os[3] = {x2o, x2a, x2aa};
        for (int enc = 0; enc < 3; enc++) {
            const int* perm = enc == 2 ? perm1 : perm0;
            const int* off  = enc == 2 ? off1 : off0;
            const int* toff = enc == 2 ? toff1 : toff0;
            const int* t2r  = enc == 2 ? t2r1 : t2r0;
            const float* w  = enc == 2 ? w1 : w0;
            k_gemm<HH1, HH2><<<MAXT, 256, 0, stream>>>(Xs[enc], msg, perm, off, toff,
                                                       t2r, w, posD, w2t, ei);
            k_reduce<HH2, false><<<NN / 4, 256, 0, stream>>>(msg, dstOff, Os[enc], nullptr);
        }
    }

    // 5) readout + discriminator + classifier
    k_mean<<<256, 256, 0, stream>>>(x2o, csum);
    k_disc<<<(NN + 255) / 256, 256, 0, stream>>>(x2o, x2a, x2aa, csum, discW, discb,
                                                 ret_os, ret_osa);
    k_cls<<<BB / 8, 256, 0, stream>>>(h1o, x2o, feat, attt, idx, clsW, clsb, log_out);
}

// Round 3
// 1046.271 us; speedup vs baseline: 1.1926x; 1.0866x over previous
//
#include <hip/hip_runtime.h>
#include <hip/hip_bf16.h>

// ---------------- problem constants ----------------
#define NN 20000      // nodes
#define EE 640000     // edges
#define RR 65         // relations
#define FIN1 128      // input feat
#define HH1 64        // hidden1
#define HH2 32        // hidden2
#define BB 8192       // pairs

constexpr int BM = 128;                 // edge-tile rows per GEMM block
constexpr int MAXT = EE / BM + RR;      // 5065 upper bound on tiles per sort

typedef __attribute__((ext_vector_type(8))) short short8;   // 8 bf16 (4 VGPRs) MFMA frag
typedef __attribute__((ext_vector_type(4))) float floatx4;  // 4 fp32 acc

// ---------------- workspace layout (bytes) ----------------
constexpr size_t aln(size_t x) { return (x + 255) & ~(size_t)255; }

constexpr size_t OFF_HIST0 = 0;                       // 65 int
constexpr size_t OFF_HIST1 = OFF_HIST0 + 65 * 4;
constexpr size_t OFF_CUR0  = OFF_HIST1 + 65 * 4;
constexpr size_t OFF_CUR1  = OFF_CUR0 + 65 * 4;
constexpr size_t OFF_CSUM  = OFF_CUR1 + 65 * 4;       // 32 float
constexpr size_t OFF_CNTD  = aln(OFF_CSUM + 32 * 4);  // NN int (per-dst degree)
constexpr size_t ZERO_BYTES = OFF_CNTD + (size_t)NN * 4;   // memset [0, ZERO_BYTES)
constexpr size_t OFF_DSTOFF = aln(ZERO_BYTES);        // NN+1 int dst CSR offsets
constexpr size_t OFF_OFF0  = aln(OFF_DSTOFF + ((size_t)NN + 1) * 4); // 66 int
constexpr size_t OFF_OFF1  = OFF_OFF0 + 66 * 4;
constexpr size_t OFF_TOFF0 = OFF_OFF1 + 66 * 4;       // 66 int tile offsets
constexpr size_t OFF_TOFF1 = OFF_TOFF0 + 66 * 4;
constexpr size_t OFF_T2R0  = aln(OFF_TOFF1 + 66 * 4); // MAXT int tile->relation
constexpr size_t OFF_T2R1  = OFF_T2R0 + (size_t)MAXT * 4;
constexpr size_t OFF_SLOT  = aln(OFF_T2R1 + (size_t)MAXT * 4);  // E int (slot in dst seg)
constexpr size_t OFF_POSD  = OFF_SLOT + (size_t)EE * 4;         // E int (dst-sorted pos)
constexpr size_t OFF_ED    = OFF_POSD + (size_t)EE * 4;         // E int (pos -> edge)
constexpr size_t OFF_RD    = OFF_ED + (size_t)EE * 4;           // E uint (pos -> r0|r1<<16)
constexpr size_t OFF_XOB   = aln(OFF_RD + (size_t)EE * 4);      // N*F bf16
constexpr size_t OFF_XAB   = OFF_XOB + (size_t)NN * FIN1 * 2;
constexpr size_t OFF_W0    = aln(OFF_XAB + (size_t)NN * FIN1 * 2); // E float
constexpr size_t OFF_W1    = OFF_W0 + (size_t)EE * 4;
constexpr size_t OFF_PERM0 = OFF_W1 + (size_t)EE * 4;           // E int
constexpr size_t OFF_PERM1 = OFF_PERM0 + (size_t)EE * 4;
constexpr size_t OFF_H1    = OFF_PERM1 + (size_t)EE * 4;        // 3 * N*64 float
constexpr size_t OFF_H1B   = OFF_H1 + (size_t)3 * NN * HH1 * 4; // 3 * N*64 bf16
constexpr size_t OFF_X2A   = OFF_H1B + (size_t)3 * NN * HH1 * 2; // N*32 float
constexpr size_t OFF_X2AA  = OFF_X2A + (size_t)NN * HH2 * 4;
constexpr size_t OFF_W1BT  = OFF_X2AA + (size_t)NN * HH2 * 4;   // R*64*128 bf16 (transposed)
constexpr size_t OFF_W2BT  = OFF_W1BT + (size_t)RR * HH1 * FIN1 * 2; // R*32*64 bf16
constexpr size_t OFF_MSG   = aln(OFF_W2BT + (size_t)RR * HH2 * HH1 * 2); // E*64 bf16
constexpr size_t WS_END    = OFF_MSG + (size_t)EE * HH1 * 2;    // ~132 MB

// output offsets (floats)
constexpr size_t O_LOG  = 0;
constexpr size_t O_ROS  = (size_t)BB * RR;          // 532480
constexpr size_t O_ROSA = O_ROS + (size_t)NN * 2;   // 572480
constexpr size_t O_X2O  = O_ROSA + (size_t)NN * 2;  // 612480

__device__ inline unsigned short f2bf(float f) {
    __hip_bfloat16 h = __float2bfloat16(f);
    return *reinterpret_cast<unsigned short*>(&h);
}
__device__ inline float bfbits2f(unsigned int hi_bits) {   // bits already in [31:16]
    return __uint_as_float(hi_bits);
}

// ---------------- preprocessing ----------------
// per-relation histograms (LDS-aggregated; no per-edge global atomics)
// + fused bf16 conversions of node features and transposed weights.
__global__ void k_prep(const int* __restrict__ et0, const int* __restrict__ et1,
                       int* hist0, int* hist1,
                       const float* __restrict__ x_o, const float* __restrict__ x_a,
                       const float* __restrict__ W1, const float* __restrict__ W2,
                       unsigned short* xob, unsigned short* xab,
                       unsigned short* w1t, unsigned short* w2t) {
    __shared__ int lh0[RR], lh1[RR];
    int t = threadIdx.x;
    if (t < RR) { lh0[t] = 0; lh1[t] = 0; }
    __syncthreads();
    int e = blockIdx.x * 256 + t;
    if (e < EE) {
        atomicAdd(&lh0[et0[e]], 1);
        atomicAdd(&lh1[et1[e]], 1);
    }
    __syncthreads();
    if (t < RR) {
        if (lh0[t]) atomicAdd(&hist0[t], lh0[t]);
        if (lh1[t]) atomicAdd(&hist1[t], lh1[t]);
    }
    // streaming conversions (grid-stride over full grid)
    int stride = gridDim.x * 256;
    int i0 = blockIdx.x * 256 + t;
    const int NX = NN * FIN1;
    for (int i = i0; i < NX; i += stride) { xob[i] = f2bf(x_o[i]); xab[i] = f2bf(x_a[i]); }
    const int NW1 = RR * HH1 * FIN1;
    for (int i = i0; i < NW1; i += stride) {
        int k = i % FIN1; int rh = i / FIN1; int hh = rh % HH1; int r = rh / HH1;
        w1t[i] = f2bf(W1[((size_t)r * FIN1 + k) * HH1 + hh]);
    }
    const int NW2 = RR * HH2 * HH1;
    for (int i = i0; i < NW2; i += stride) {
        int k = i % HH1; int rh = i / HH1; int hh = rh % HH2; int r = rh / HH2;
        w2t[i] = f2bf(W2[((size_t)r * HH1 + k) * HH2 + hh]);
    }
}

// relation bucket offsets, tile offsets, tile->relation maps (single block)
__global__ void k_scanR(const int* __restrict__ hist0, const int* __restrict__ hist1,
                        int* off0, int* off1, int* toff0, int* toff1,
                        int* t2r0, int* t2r1) {
    __shared__ int h[2][RR];
    __shared__ int o[2][RR + 1], to[2][RR + 1];
    int t = threadIdx.x;
    if (t < RR) { h[0][t] = hist0[t]; h[1][t] = hist1[t]; }
    __syncthreads();
    if (t == 0) {
        for (int s = 0; s < 2; s++) {
            int a = 0, b = 0;
            for (int r = 0; r < RR; r++) {
                o[s][r] = a; to[s][r] = b;
                a += h[s][r]; b += (h[s][r] + BM - 1) / BM;
            }
            o[s][RR] = a; to[s][RR] = b;
        }
    }
    __syncthreads();
    if (t <= RR) { off0[t] = o[0][t]; off1[t] = o[1][t]; toff0[t] = to[0][t]; toff1[t] = to[1][t]; }
    for (int i = t; i < MAXT; i += blockDim.x) {
        for (int s = 0; s < 2; s++) {
            int total = to[s][RR];
            int r = -1;
            if (i < total) {
                int lo = 0, hi = RR;
                while (hi - lo > 1) { int mid = (lo + hi) >> 1; if (to[s][mid] <= i) lo = mid; else hi = mid; }
                r = lo;
            }
            (s ? t2r1 : t2r0)[i] = r;
        }
    }
}

// relation-sorted perm placement (LDS-aggregated) + per-dst slot via the ONE
// remaining per-edge global atomic.
__global__ void k_fill(const int* __restrict__ ei, const int* __restrict__ et0,
                       const int* __restrict__ et1,
                       const int* __restrict__ off0, const int* __restrict__ off1,
                       int* cur0, int* cur1, int* perm0, int* perm1,
                       int* cntD, int* slotE) {
    __shared__ int lh[2][RR];
    __shared__ int lbase[2][RR];
    int t = threadIdx.x;
    if (t < RR) { lh[0][t] = 0; lh[1][t] = 0; }
    __syncthreads();
    int e = blockIdx.x * 256 + t;
    int r0 = 0, r1 = 0, p0 = 0, p1 = 0;
    bool v = e < EE;
    if (v) {
        r0 = et0[e]; r1 = et1[e];
        p0 = atomicAdd(&lh[0][r0], 1);
        p1 = atomicAdd(&lh[1][r1], 1);
    }
    __syncthreads();
    if (t < RR) {
        lbase[0][t] = lh[0][t] ? atomicAdd(&cur0[t], lh[0][t]) : 0;
        lbase[1][t] = lh[1][t] ? atomicAdd(&cur1[t], lh[1][t]) : 0;
    }
    __syncthreads();
    if (v) {
        perm0[off0[r0] + lbase[0][r0] + p0] = e;
        perm1[off1[r1] + lbase[1][r1] + p1] = e;
        int d = ei[EE + e];
        slotE[e] = atomicAdd(&cntD[d], 1);
    }
}

// exclusive scan of per-dst degrees -> dstOff[NN+1] (single block, 256 threads)
__global__ void k_scanD(const int* __restrict__ cntD, int* __restrict__ dstOff) {
    __shared__ int s[256];
    int t = threadIdx.x;
    constexpr int PER = (NN + 255) / 256;   // 79
    int lo = t * PER, hi = min(NN, lo + PER);
    int sum = 0;
    for (int i = lo; i < hi; i++) sum += cntD[i];
    s[t] = sum;
    __syncthreads();
    for (int ofs = 1; ofs < 256; ofs <<= 1) {
        int v = 0;
        if (t >= ofs) v = s[t - ofs];
        __syncthreads();
        if (t >= ofs) s[t] += v;
        __syncthreads();
    }
    int run = s[t] - sum;   // exclusive base
    for (int i = lo; i < hi; i++) { dstOff[i] = run; run += cntD[i]; }
    if (t == 255) dstOff[NN] = run;
}

// posD / inverse map / packed relations per dst-sorted slot
__global__ void k_post(const int* __restrict__ ei, const int* __restrict__ et0,
                       const int* __restrict__ et1, const int* __restrict__ dstOff,
                       const int* __restrict__ slotE,
                       int* posD, int* eD, unsigned int* rD) {
    int e = blockIdx.x * 256 + threadIdx.x;
    if (e < EE) {
        int d = ei[EE + e];
        int pos = dstOff[d] + slotE[e];
        posD[e] = pos;
        eD[pos] = e;
        rD[pos] = (unsigned)et0[e] | ((unsigned)et1[e] << 16);
    }
}

// per-(relation,dst) mean weights computed inside each dst segment (no atomics):
// w0[e] = 1 / #{e' in segment(dst): et0[e']==et0[e]}, same for w1.
__global__ void k_weights(const int* __restrict__ dstOff, const int* __restrict__ eD,
                          const unsigned int* __restrict__ rD,
                          float* __restrict__ w0, float* __restrict__ w1) {
    constexpr int CAP = 96;
    __shared__ unsigned int ld[4][CAP];
    int wave = threadIdx.x >> 6;
    int lane = threadIdx.x & 63;
    int d = blockIdx.x * 4 + wave;
    int j0 = 0, deg = 0;
    if (d < NN) { j0 = dstOff[d]; deg = dstOff[d + 1] - j0; }
    for (int j = lane; j < deg && j < CAP; j += 64) ld[wave][j] = rD[j0 + j];
    __syncthreads();
    for (int j = lane; j < deg; j += 64) {
        unsigned int my = (j < CAP) ? ld[wave][j] : rD[j0 + j];
        unsigned int m0 = my & 0xffffu, m1 = my >> 16;
        int c0 = 0, c1 = 0;
        for (int k = 0; k < deg; k++) {
            unsigned int p = (k < CAP) ? ld[wave][k] : rD[j0 + k];
            c0 += ((p & 0xffffu) == m0);
            c1 += ((p >> 16) == m1);
        }
        int e = eD[j0 + j];
        w0[e] = 1.0f / (float)c0;
        w1[e] = 1.0f / (float)c1;
    }
}

// root term: out[n,h] = x[n,:]@root[:,h] + b[h]   (fp32, full precision)
template <int FIN, int HOUT>
__global__ void k_base(const float* __restrict__ x0, const float* __restrict__ x1,
                       const float* __restrict__ x2,
                       const float* __restrict__ root, const float* __restrict__ bias,
                       float* o0, float* o1, float* o2) {
    const float* x = blockIdx.y == 0 ? x0 : (blockIdx.y == 1 ? x1 : x2);
    float* o = blockIdx.y == 0 ? o0 : (blockIdx.y == 1 ? o1 : o2);
    int lane = threadIdx.x % HOUT;
    int sub = threadIdx.x / HOUT;
    int n = blockIdx.x * (256 / HOUT) + sub;
    if (n >= NN) return;
    const float4* xr = (const float4*)(x + (size_t)n * FIN);
    float acc = bias[lane];
    #pragma unroll 4
    for (int f4 = 0; f4 < FIN / 4; f4++) {
        float4 xv = xr[f4];
        int f = f4 * 4;
        acc += xv.x * root[(f + 0) * HOUT + lane];
        acc += xv.y * root[(f + 1) * HOUT + lane];
        acc += xv.z * root[(f + 2) * HOUT + lane];
        acc += xv.w * root[(f + 3) * HOUT + lane];
    }
    o[(size_t)n * HOUT + lane] = acc;
}

// relation-grouped gather-GEMM with MFMA; epilogue writes weighted bf16 msg rows
// to dst-sorted slots (full-cacheline plain stores — no RMW atomics).
template <int FIN, int HOUT>
__launch_bounds__(256, (FIN == 128 ? 3 : 4))
__global__ void k_gemm(const unsigned short* __restrict__ X,
                       unsigned short* __restrict__ msg,
                       const int* __restrict__ perm, const int* __restrict__ off,
                       const int* __restrict__ toff, const int* __restrict__ t2r,
                       const float* __restrict__ w, const int* __restrict__ posD,
                       const unsigned short* __restrict__ WT,  // [R][HOUT][FIN] bf16
                       const int* __restrict__ ei) {
    int b = blockIdx.x;
    int r = t2r[b];
    if (r < 0) return;
    int t = b - toff[r];
    int ebase = off[r] + t * BM;
    int mcount = min(BM, off[r + 1] - ebase);

    constexpr int LDK = FIN + 8;  // +8 bf16 pad
    __shared__ unsigned short As[BM][LDK];
    __shared__ unsigned short Bs[HOUT][LDK];
    __shared__ int Sr[BM];
    __shared__ float Ww[BM];
    __shared__ int Pd[BM];

    int tid = threadIdx.x;
    if (tid < BM) {
        if (tid < mcount) {
            int e = perm[ebase + tid];
            Sr[tid] = ei[e];
            Ww[tid] = w[e];
            Pd[tid] = posD[e];
        } else { Sr[tid] = -1; Ww[tid] = 0.f; Pd[tid] = 0; }
    }
    __syncthreads();

    // stage B (W[r] transposed rows, 16B chunks)
    {
        const unsigned short* Wr = WT + (size_t)r * HOUT * FIN;
        constexpr int CHB = HOUT * FIN / 8;
        for (int c = tid; c < CHB; c += 256) {
            int row = c / (FIN / 8), cc = c % (FIN / 8);
            *(uint4*)&Bs[row][cc * 8] = *(const uint4*)&Wr[row * FIN + cc * 8];
        }
    }
    // stage A (gathered node rows)
    {
        constexpr int CHA = BM * FIN / 8;
        for (int c = tid; c < CHA; c += 256) {
            int row = c / (FIN / 8), cc = c % (FIN / 8);
            int s = Sr[row];
            uint4 v = {0u, 0u, 0u, 0u};
            if (s >= 0) v = *(const uint4*)&X[(size_t)s * FIN + cc * 8];
            *(uint4*)&As[row][cc * 8] = v;
        }
    }
    __syncthreads();

    const int wave = tid >> 6;      // 4 waves; each: 32 edges x HOUT
    const int lane = tid & 63;
    const int q = lane >> 4;
    const int ln = lane & 15;
    constexpr int NT = HOUT / 16;
    constexpr int KS = FIN / 32;
    const int mbase = wave * 32;

    floatx4 acc[2][NT];
    #pragma unroll
    for (int a = 0; a < 2; a++)
        #pragma unroll
        for (int nt = 0; nt < NT; nt++) acc[a][nt] = floatx4{0.f, 0.f, 0.f, 0.f};

    for (int ks = 0; ks < KS; ks++) {
        int kk = ks * 32 + q * 8;
        short8 af0 = *(const short8*)&As[mbase + ln][kk];
        short8 af1 = *(const short8*)&As[mbase + 16 + ln][kk];
        #pragma unroll
        for (int nt = 0; nt < NT; nt++) {
            short8 bf = *(const short8*)&Bs[nt * 16 + ln][kk];
            acc[0][nt] = __builtin_amdgcn_mfma_f32_16x16x32_bf16(af0, bf, acc[0][nt], 0, 0, 0);
            acc[1][nt] = __builtin_amdgcn_mfma_f32_16x16x32_bf16(af1, bf, acc[1][nt], 0, 0, 0);
        }
    }

    // epilogue: transpose weighted bf16 msgs through LDS (overlay As), then
    // coalesced full-line scatter to msg[posD[e]*HOUT .. +HOUT)
    __syncthreads();
    constexpr int LDM = HOUT + 8;   // pad to stagger banks; row stride %16B == 0
    unsigned short* Ms = &As[0][0];
    #pragma unroll
    for (int mt = 0; mt < 2; mt++) {
        #pragma unroll
        for (int rr2 = 0; rr2 < 4; rr2++) {
            int i = mbase + mt * 16 + q * 4 + rr2;
            float wt = Ww[i];
            #pragma unroll
            for (int nt = 0; nt < NT; nt++)
                Ms[i * LDM + nt * 16 + ln] = f2bf(wt * acc[mt][nt][rr2]);
        }
    }
    __syncthreads();
    constexpr int CH = HOUT / 8;    // 16B chunks per row
    for (int c = tid; c < BM * CH; c += 256) {
        int row = c / CH, cc = c % CH;
        if (row < mcount)
            *(uint4*)&msg[(size_t)Pd[row] * HOUT + cc * 8] = *(const uint4*)&Ms[row * LDM + cc * 8];
    }
}

// segment-sum msg rows per dst (contiguous in dst-sorted order), add root base,
// optional fused relu + bf16 cast. One wave per dst; 8B loads per lane.
template <int H, bool RELU>
__global__ void k_reduce(const unsigned short* __restrict__ msg,
                         const int* __restrict__ dstOff,
                         float* __restrict__ base_io,
                         unsigned short* __restrict__ bfout) {
    int d = blockIdx.x * 4 + (threadIdx.x >> 6);
    if (d >= NN) return;
    int lane = threadIdx.x & 63;
    constexpr int HC = H / 4;          // 8B chunks per row (H=64 -> 16, H=32 -> 8)
    constexpr int RPI = 64 / HC;       // rows per iteration
    int sub = lane / HC;
    int c4 = lane % HC;
    int j0 = dstOff[d], j1 = dstOff[d + 1];
    float a0 = 0.f, a1 = 0.f, a2 = 0.f, a3 = 0.f;
    for (int j = j0 + sub; j < j1; j += RPI) {
        uint2 v = *(const uint2*)&msg[(size_t)j * H + c4 * 4];
        a0 += bfbits2f(v.x << 16);
        a1 += bfbits2f(v.x & 0xffff0000u);
        a2 += bfbits2f(v.y << 16);
        a3 += bfbits2f(v.y & 0xffff0000u);
    }
    #pragma unroll
    for (int ofs = 32; ofs >= HC; ofs >>= 1) {
        a0 += __shfl_down(a0, ofs); a1 += __shfl_down(a1, ofs);
        a2 += __shfl_down(a2, ofs); a3 += __shfl_down(a3, ofs);
    }
    if (lane < HC) {
        size_t o = (size_t)d * H + c4 * 4;
        float v0 = base_io[o] + a0, v1 = base_io[o + 1] + a1;
        float v2 = base_io[o + 2] + a2, v3 = base_io[o + 3] + a3;
        if (RELU) {
            v0 = fmaxf(v0, 0.f); v1 = fmaxf(v1, 0.f);
            v2 = fmaxf(v2, 0.f); v3 = fmaxf(v3, 0.f);
        }
        base_io[o] = v0; base_io[o + 1] = v1; base_io[o + 2] = v2; base_io[o + 3] = v3;
        if (RELU) {
            bfout[o] = f2bf(v0); bfout[o + 1] = f2bf(v1);
            bfout[o + 2] = f2bf(v2); bfout[o + 3] = f2bf(v3);
        }
    }
}

// column sums of x2_o -> csum[32]
__global__ void k_mean(const float* __restrict__ x2o, float* csum) {
    __shared__ float s[256];
    int t = threadIdx.x; int hh = t & 31; int g = t >> 5;
    float acc = 0.f;
    for (int n = blockIdx.x * 8 + g; n < NN; n += gridDim.x * 8)
        acc += x2o[(size_t)n * 32 + hh];
    s[t] = acc;
    __syncthreads();
    if (t < 32) {
        float v = 0.f;
        for (int gg = 0; gg < 8; gg++) v += s[gg * 32 + t];
        unsafeAtomicAdd(&csum[t], v);
    }
}

// c = sigmoid(csum/N); v = disc_W @ c; bilinear scores
__global__ void k_disc(const float* __restrict__ x2o, const float* __restrict__ x2a,
                       const float* __restrict__ x2aa, const float* __restrict__ csum,
                       const float* __restrict__ discW, const float* __restrict__ discb,
                       float* ret_os, float* ret_osa) {
    __shared__ float c[32], v[32];
    int t = threadIdx.x;
    if (t < 32) c[t] = 1.f / (1.f + expf(-csum[t] * (1.f / NN)));
    __syncthreads();
    if (t < 32) {
        float a = 0.f;
        for (int j = 0; j < 32; j++) a += discW[t * 32 + j] * c[j];
        v[t] = a;
    }
    __syncthreads();
    float db = discb[0];
    int n = blockIdx.x * 256 + t;
    if (n < NN) {
        float s1 = 0.f, s2 = 0.f, s3 = 0.f;
        for (int j = 0; j < 32; j++) {
            float vj = v[j];
            s1 += x2o[(size_t)n * 32 + j] * vj;
            s2 += x2a[(size_t)n * 32 + j] * vj;
            s3 += x2aa[(size_t)n * 32 + j] * vj;
        }
        ret_os[n * 2] = s1 + db;  ret_os[n * 2 + 1] = s2 + db;
        ret_osa[n * 2] = s1 + db; ret_osa[n * 2 + 1] = s3 + db;
    }
}

// pair classifier: e(448) @ cls_W(448x65) + cls_b; 8 pairs per block staged in LDS
__global__ void k_cls(const float* __restrict__ h1o, const float* __restrict__ x2o,
                      const float* __restrict__ feat, const float* __restrict__ attt,
                      const int* __restrict__ idx, const float* __restrict__ clsW,
                      const float* __restrict__ clsb, float* __restrict__ log_out) {
    __shared__ float ev[8][448];
    int t = threadIdx.x;
    int b0 = blockIdx.x * 8;
    float a0 = attt[0], a1 = attt[1];
    for (int x = t; x < 8 * 448; x += 256) {
        int bb = x / 448, j = x % 448;
        int pair = b0 + bb;
        int hseg = j / 224;
        int jj = j % 224;
        int node = idx[hseg * BB + pair];
        float val;
        if (jj < 64) val = a0 * h1o[(size_t)node * 64 + jj];
        else if (jj < 96) val = a1 * x2o[(size_t)node * 32 + (jj - 64)];
        else val = feat[(size_t)node * 128 + (jj - 96)];
        ev[bb][j] = val;
    }
    __syncthreads();
    for (int o = t; o < 8 * RR; o += 256) {
        int bb = o / RR, r = o % RR;
        const float* e = ev[bb];
        float acc = clsb[r];
        #pragma unroll 8
        for (int f = 0; f < 448; f++) acc += e[f] * clsW[f * RR + r];
        log_out[(size_t)(b0 + bb) * RR + r] = acc;
    }
}

extern "C" void kernel_launch(void* const* d_in, const int* in_sizes, int n_in,
                              void* d_out, int out_size, void* d_ws, size_t ws_size,
                              hipStream_t stream) {
    const float* x_o   = (const float*)d_in[0];
    const float* x_a   = (const float*)d_in[1];
    const float* feat  = (const float*)d_in[2];
    const float* W1    = (const float*)d_in[3];
    const float* root1 = (const float*)d_in[4];
    const float* b1    = (const float*)d_in[5];
    const float* W2    = (const float*)d_in[6];
    const float* root2 = (const float*)d_in[7];
    const float* b2    = (const float*)d_in[8];
    const float* attt  = (const float*)d_in[9];
    const float* discW = (const float*)d_in[10];
    const float* discb = (const float*)d_in[11];
    const float* clsW  = (const float*)d_in[12];
    const float* clsb  = (const float*)d_in[13];
    const int* ei      = (const int*)d_in[14];
    const int* et0     = (const int*)d_in[15];
    const int* et1     = (const int*)d_in[16];
    const int* idx     = (const int*)d_in[17];

    char* ws = (char*)d_ws;
    int* hist0 = (int*)(ws + OFF_HIST0);
    int* hist1 = (int*)(ws + OFF_HIST1);
    int* cur0  = (int*)(ws + OFF_CUR0);
    int* cur1  = (int*)(ws + OFF_CUR1);
    float* csum = (float*)(ws + OFF_CSUM);
    int* cntD  = (int*)(ws + OFF_CNTD);
    int* dstOff = (int*)(ws + OFF_DSTOFF);
    int* off0  = (int*)(ws + OFF_OFF0);
    int* off1  = (int*)(ws + OFF_OFF1);
    int* toff0 = (int*)(ws + OFF_TOFF0);
    int* toff1 = (int*)(ws + OFF_TOFF1);
    int* t2r0  = (int*)(ws + OFF_T2R0);
    int* t2r1  = (int*)(ws + OFF_T2R1);
    int* slotE = (int*)(ws + OFF_SLOT);
    int* posD  = (int*)(ws + OFF_POSD);
    int* eD    = (int*)(ws + OFF_ED);
    unsigned int* rD = (unsigned int*)(ws + OFF_RD);
    unsigned short* xob = (unsigned short*)(ws + OFF_XOB);
    unsigned short* xab = (unsigned short*)(ws + OFF_XAB);
    float* w0 = (float*)(ws + OFF_W0);
    float* w1 = (float*)(ws + OFF_W1);
    int* perm0 = (int*)(ws + OFF_PERM0);
    int* perm1 = (int*)(ws + OFF_PERM1);
    float* h1o  = (float*)(ws + OFF_H1);
    float* h1a  = h1o + (size_t)NN * HH1;
    float* h1aa = h1a + (size_t)NN * HH1;
    unsigned short* h1bo  = (unsigned short*)(ws + OFF_H1B);
    unsigned short* h1ba  = h1bo + (size_t)NN * HH1;
    unsigned short* h1baa = h1ba + (size_t)NN * HH1;
    float* x2a  = (float*)(ws + OFF_X2A);
    float* x2aa = (float*)(ws + OFF_X2AA);
    unsigned short* w1t = (unsigned short*)(ws + OFF_W1BT);
    unsigned short* w2t = (unsigned short*)(ws + OFF_W2BT);
    unsigned short* msg = (unsigned short*)(ws + OFF_MSG);

    float* out = (float*)d_out;
    float* log_out = out + O_LOG;
    float* ret_os  = out + O_ROS;
    float* ret_osa = out + O_ROSA;
    float* x2o     = out + O_X2O;

    // 1) zero control block (hist/cur/csum/cntD) — ~160 KB only
    hipMemsetAsync(ws, 0, ZERO_BYTES, stream);

    // 2) preprocessing
    k_prep<<<2500, 256, 0, stream>>>(et0, et1, hist0, hist1,
                                     x_o, x_a, W1, W2, xob, xab, w1t, w2t);
    k_scanR<<<1, 256, 0, stream>>>(hist0, hist1, off0, off1, toff0, toff1, t2r0, t2r1);
    k_fill<<<2500, 256, 0, stream>>>(ei, et0, et1, off0, off1,
                                     cur0, cur1, perm0, perm1, cntD, slotE);
    k_scanD<<<1, 256, 0, stream>>>(cntD, dstOff);
    k_post<<<2500, 256, 0, stream>>>(ei, et0, et1, dstOff, slotE, posD, eD, rD);
    k_weights<<<NN / 4, 256, 0, stream>>>(dstOff, eD, rD, w0, w1);

    // 3) layer 1: base + per-encoding (edge GEMM -> dst reduce with fused relu/cvt)
    dim3 gb1(5000, 3);
    k_base<FIN1, HH1><<<gb1, 256, 0, stream>>>(x_o, x_a, x_o, root1, b1, h1o, h1a, h1aa);
    {
        const unsigned short* Xs[3] = {xob, xab, xob};
        float* Os[3] = {h1o, h1a, h1aa};
        unsigned short* Obs[3] = {h1bo, h1ba, h1baa};
        for (int enc = 0; enc < 3; enc++) {
            const int* perm = enc == 2 ? perm1 : perm0;
            const int* off  = enc == 2 ? off1 : off0;
            const int* toff = enc == 2 ? toff1 : toff0;
            const int* t2r  = enc == 2 ? t2r1 : t2r0;
            const float* w  = enc == 2 ? w1 : w0;
            k_gemm<FIN1, HH1><<<MAXT, 256, 0, stream>>>(Xs[enc], msg, perm, off, toff,
                                                        t2r, w, posD, w1t, ei);
            k_reduce<HH1, true><<<NN / 4, 256, 0, stream>>>(msg, dstOff, Os[enc], Obs[enc]);
        }
    }

    // 4) layer 2: base + per-encoding (edge GEMM -> dst reduce)
    dim3 gb2(2500, 3);
    k_base<HH1, HH2><<<gb2, 256, 0, stream>>>(h1o, h1a, h1aa, root2, b2, x2o, x2a, x2aa);
    {
        const unsigned short* Xs[3] = {h1bo, h1ba, h1baa};
        float* Os[3] = {x2o, x2a, x2aa};
        for (int enc = 0; enc < 3; enc++) {
            const int* perm = enc == 2 ? perm1 : perm0;
            const int* off  = enc == 2 ? off1 : off0;
            const int* toff = enc == 2 ? toff1 : toff0;
            const int* t2r  = enc == 2 ? t2r1 : t2r0;
            const float* w  = enc == 2 ? w1 : w0;
            k_gemm<HH1, HH2><<<MAXT, 256, 0, stream>>>(Xs[enc], msg, perm, off, toff,
                                                       t2r, w, posD, w2t, ei);
            k_reduce<HH2, false><<<NN / 4, 256, 0, stream>>>(msg, dstOff, Os[enc], nullptr);
        }
    }

    // 5) readout + discriminator + classifier
    k_mean<<<256, 256, 0, stream>>>(x2o, csum);
    k_disc<<<(NN + 255) / 256, 256, 0, stream>>>(x2o, x2a, x2aa, csum, discW, discb,
                                                 ret_os, ret_osa);
    k_cls<<<BB / 8, 256, 0, stream>>>(h1o, x2o, feat, attt, idx, clsW, clsb, log_out);
}

// Round 4
// 915.832 us; speedup vs baseline: 1.3624x; 1.1424x over previous
//
#include <hip/hip_runtime.h>
#include <hip/hip_bf16.h>

// ---------------- problem constants ----------------
#define NN 20000      // nodes
#define EE 640000     // edges
#define RR 65         // relations
#define FIN1 128      // input feat
#define HH1 64        // hidden1
#define HH2 32        // hidden2
#define BB 8192       // pairs

constexpr int BM = 128;                 // edge-tile rows per GEMM block
constexpr int MAXT = EE / BM + RR;      // 5065 upper bound on tiles per sort
constexpr int NBH = 256;                // histogram/placement blocks
constexpr int EPB = EE / NBH;           // 2500 edges per block

typedef __attribute__((ext_vector_type(8))) short short8;   // 8 bf16 (4 VGPRs) MFMA frag
typedef __attribute__((ext_vector_type(4))) float floatx4;  // 4 fp32 acc

// ---------------- workspace layout (bytes) ----------------
constexpr size_t aln(size_t x) { return (x + 255) & ~(size_t)255; }

constexpr size_t OFF_CSUM  = 0;                       // 32 float
constexpr size_t OFF_CNTD  = aln(OFF_CSUM + 32 * 4); // NN int (per-dst degree)
constexpr size_t ZERO_BYTES = OFF_CNTD + (size_t)NN * 4;   // memset [0, ZERO_BYTES)
constexpr size_t OFF_BH0   = aln(ZERO_BYTES);         // NBH*RR int block hists
constexpr size_t OFF_BH1   = OFF_BH0 + (size_t)NBH * RR * 4;
constexpr size_t OFF_BB0   = OFF_BH1 + (size_t)NBH * RR * 4;  // NBH*RR int block bases
constexpr size_t OFF_BB1   = OFF_BB0 + (size_t)NBH * RR * 4;
constexpr size_t OFF_DSTOFF = aln(OFF_BB1 + (size_t)NBH * RR * 4); // NN+1 int
constexpr size_t OFF_OFF0  = aln(OFF_DSTOFF + ((size_t)NN + 1) * 4); // 66 int
constexpr size_t OFF_OFF1  = OFF_OFF0 + 66 * 4;
constexpr size_t OFF_TOFF0 = OFF_OFF1 + 66 * 4;       // 66 int tile offsets
constexpr size_t OFF_TOFF1 = OFF_TOFF0 + 66 * 4;
constexpr size_t OFF_T2R0  = aln(OFF_TOFF1 + 66 * 4); // MAXT int tile->relation
constexpr size_t OFF_T2R1  = OFF_T2R0 + (size_t)MAXT * 4;
constexpr size_t OFF_SLOT  = aln(OFF_T2R1 + (size_t)MAXT * 4);  // E int (slot in dst seg)
constexpr size_t OFF_POSD  = OFF_SLOT + (size_t)EE * 4;         // E int (dst-sorted pos)
constexpr size_t OFF_ED    = OFF_POSD + (size_t)EE * 4;         // E int (pos -> edge)
constexpr size_t OFF_RD    = OFF_ED + (size_t)EE * 4;           // E uint (pos -> r0|r1<<16)
constexpr size_t OFF_XOB   = aln(OFF_RD + (size_t)EE * 4);      // N*F bf16
constexpr size_t OFF_XAB   = OFF_XOB + (size_t)NN * FIN1 * 2;
constexpr size_t OFF_W0    = aln(OFF_XAB + (size_t)NN * FIN1 * 2); // E float
constexpr size_t OFF_W1    = OFF_W0 + (size_t)EE * 4;
constexpr size_t OFF_PERM0 = OFF_W1 + (size_t)EE * 4;           // E int
constexpr size_t OFF_PERM1 = OFF_PERM0 + (size_t)EE * 4;
constexpr size_t OFF_H1    = OFF_PERM1 + (size_t)EE * 4;        // 3 * N*64 float
constexpr size_t OFF_H1B   = OFF_H1 + (size_t)3 * NN * HH1 * 4; // 3 * N*64 bf16
constexpr size_t OFF_X2A   = OFF_H1B + (size_t)3 * NN * HH1 * 2; // N*32 float
constexpr size_t OFF_X2AA  = OFF_X2A + (size_t)NN * HH2 * 4;
constexpr size_t OFF_W1BT  = OFF_X2AA + (size_t)NN * HH2 * 4;   // R*64*128 bf16 (transposed)
constexpr size_t OFF_W2BT  = OFF_W1BT + (size_t)RR * HH1 * FIN1 * 2; // R*32*64 bf16
constexpr size_t OFF_MSG   = aln(OFF_W2BT + (size_t)RR * HH2 * HH1 * 2); // E*64 bf16
constexpr size_t WS_END    = OFF_MSG + (size_t)EE * HH1 * 2;    // ~132 MB

// output offsets (floats)
constexpr size_t O_LOG  = 0;
constexpr size_t O_ROS  = (size_t)BB * RR;          // 532480
constexpr size_t O_ROSA = O_ROS + (size_t)NN * 2;   // 572480
constexpr size_t O_X2O  = O_ROSA + (size_t)NN * 2;  // 612480

__device__ inline unsigned short f2bf(float f) {
    __hip_bfloat16 h = __float2bfloat16(f);
    return *reinterpret_cast<unsigned short*>(&h);
}
__device__ inline float bfbits2f(unsigned int hi_bits) {   // bits already in [31:16]
    return __uint_as_float(hi_bits);
}

// ---------------- preprocessing ----------------
// per-block relation histograms via LDS, plain stores to blockHist (NO global
// atomics) + fused bf16 conversions of node features and transposed weights.
__global__ void k_hist(const int* __restrict__ et0, const int* __restrict__ et1,
                       int* __restrict__ bh0, int* __restrict__ bh1,
                       const float* __restrict__ x_o, const float* __restrict__ x_a,
                       const float* __restrict__ W1, const float* __restrict__ W2,
                       unsigned short* xob, unsigned short* xab,
                       unsigned short* w1t, unsigned short* w2t) {
    __shared__ int lh0[RR], lh1[RR];
    int t = threadIdx.x;
    if (t < RR) { lh0[t] = 0; lh1[t] = 0; }
    __syncthreads();
    int base = blockIdx.x * EPB;
    for (int i = t; i < EPB; i += 256) {
        atomicAdd(&lh0[et0[base + i]], 1);
        atomicAdd(&lh1[et1[base + i]], 1);
    }
    __syncthreads();
    if (t < RR) {
        bh0[blockIdx.x * RR + t] = lh0[t];
        bh1[blockIdx.x * RR + t] = lh1[t];
    }
    // streaming conversions (grid-stride over 256-block grid)
    int stride = gridDim.x * 256;
    int i0 = blockIdx.x * 256 + t;
    const int NX = NN * FIN1;
    for (int i = i0; i < NX; i += stride) { xob[i] = f2bf(x_o[i]); xab[i] = f2bf(x_a[i]); }
    const int NW1 = RR * HH1 * FIN1;
    for (int i = i0; i < NW1; i += stride) {
        int k = i % FIN1; int rh = i / FIN1; int hh = rh % HH1; int r = rh / HH1;
        w1t[i] = f2bf(W1[((size_t)r * FIN1 + k) * HH1 + hh]);
    }
    const int NW2 = RR * HH2 * HH1;
    for (int i = i0; i < NW2; i += stride) {
        int k = i % HH1; int rh = i / HH1; int hh = rh % HH2; int r = rh / HH2;
        w2t[i] = f2bf(W2[((size_t)r * HH1 + k) * HH2 + hh]);
    }
}

// per-relation scan over blocks -> blockBase (within-relation exclusive prefix),
// then relation bucket offsets, tile offsets, tile->relation maps. Single block.
__global__ void k_scanR(const int* __restrict__ bh0, const int* __restrict__ bh1,
                        int* __restrict__ bb0, int* __restrict__ bb1,
                        int* off0, int* off1, int* toff0, int* toff1,
                        int* t2r0, int* t2r1) {
    __shared__ int h[2][RR];
    __shared__ int o[2][RR + 1], to[2][RR + 1];
    int t = threadIdx.x;
    if (t < 2 * RR) {
        int s = t / RR, r = t % RR;
        const int* bh = s ? bh1 : bh0;
        int* bb = s ? bb1 : bb0;
        int run = 0;
        for (int b = 0; b < NBH; b++) {
            int v = bh[b * RR + r];
            bb[b * RR + r] = run;
            run += v;
        }
        h[s][r] = run;
    }
    __syncthreads();
    if (t == 0) {
        for (int s = 0; s < 2; s++) {
            int a = 0, b = 0;
            for (int r = 0; r < RR; r++) {
                o[s][r] = a; to[s][r] = b;
                a += h[s][r]; b += (h[s][r] + BM - 1) / BM;
            }
            o[s][RR] = a; to[s][RR] = b;
        }
    }
    __syncthreads();
    if (t <= RR) { off0[t] = o[0][t]; off1[t] = o[1][t]; toff0[t] = to[0][t]; toff1[t] = to[1][t]; }
    for (int i = t; i < MAXT; i += blockDim.x) {
        for (int s = 0; s < 2; s++) {
            int total = to[s][RR];
            int r = -1;
            if (i < total) {
                int lo = 0, hi = RR;
                while (hi - lo > 1) { int mid = (lo + hi) >> 1; if (to[s][mid] <= i) lo = mid; else hi = mid; }
                r = lo;
            }
            (s ? t2r1 : t2r0)[i] = r;
        }
    }
}

// relation-sorted perm placement with deterministic bases (NO small-array global
// atomics). Only the benign 20k-address cntD scatter atomic remains.
__global__ void k_fill(const int* __restrict__ ei, const int* __restrict__ et0,
                       const int* __restrict__ et1,
                       const int* __restrict__ off0, const int* __restrict__ off1,
                       const int* __restrict__ bb0, const int* __restrict__ bb1,
                       int* perm0, int* perm1, int* cntD, int* slotE) {
    __shared__ int lc[2][RR];
    __shared__ int lb[2][RR];
    int t = threadIdx.x;
    if (t < RR) {
        lc[0][t] = 0; lc[1][t] = 0;
        lb[0][t] = off0[t] + bb0[blockIdx.x * RR + t];
        lb[1][t] = off1[t] + bb1[blockIdx.x * RR + t];
    }
    __syncthreads();
    int base = blockIdx.x * EPB;
    for (int i = t; i < EPB; i += 256) {
        int e = base + i;
        int r0 = et0[e], r1 = et1[e];
        int p0 = atomicAdd(&lc[0][r0], 1);
        int p1 = atomicAdd(&lc[1][r1], 1);
        perm0[lb[0][r0] + p0] = e;
        perm1[lb[1][r1] + p1] = e;
        slotE[e] = atomicAdd(&cntD[ei[EE + e]], 1);
    }
}

// exclusive scan of per-dst degrees -> dstOff[NN+1] (single block, 256 threads)
__global__ void k_scanD(const int* __restrict__ cntD, int* __restrict__ dstOff) {
    __shared__ int s[256];
    int t = threadIdx.x;
    constexpr int PER = (NN + 255) / 256;   // 79
    int lo = t * PER, hi = min(NN, lo + PER);
    int sum = 0;
    for (int i = lo; i < hi; i++) sum += cntD[i];
    s[t] = sum;
    __syncthreads();
    for (int ofs = 1; ofs < 256; ofs <<= 1) {
        int v = 0;
        if (t >= ofs) v = s[t - ofs];
        __syncthreads();
        if (t >= ofs) s[t] += v;
        __syncthreads();
    }
    int run = s[t] - sum;   // exclusive base
    for (int i = lo; i < hi; i++) { dstOff[i] = run; run += cntD[i]; }
    if (t == 255) dstOff[NN] = run;
}

// posD / inverse map / packed relations per dst-sorted slot
__global__ void k_post(const int* __restrict__ ei, const int* __restrict__ et0,
                       const int* __restrict__ et1, const int* __restrict__ dstOff,
                       const int* __restrict__ slotE,
                       int* posD, int* eD, unsigned int* rD) {
    int e = blockIdx.x * 256 + threadIdx.x;
    if (e < EE) {
        int d = ei[EE + e];
        int pos = dstOff[d] + slotE[e];
        posD[e] = pos;
        eD[pos] = e;
        rD[pos] = (unsigned)et0[e] | ((unsigned)et1[e] << 16);
    }
}

// per-(relation,dst) mean weights computed inside each dst segment (no atomics):
// w0[e] = 1 / #{e' in segment(dst): et0[e']==et0[e]}, same for w1.
__global__ void k_weights(const int* __restrict__ dstOff, const int* __restrict__ eD,
                          const unsigned int* __restrict__ rD,
                          float* __restrict__ w0, float* __restrict__ w1) {
    constexpr int CAP = 96;
    __shared__ unsigned int ld[4][CAP];
    int wave = threadIdx.x >> 6;
    int lane = threadIdx.x & 63;
    int d = blockIdx.x * 4 + wave;
    int j0 = 0, deg = 0;
    if (d < NN) { j0 = dstOff[d]; deg = dstOff[d + 1] - j0; }
    for (int j = lane; j < deg && j < CAP; j += 64) ld[wave][j] = rD[j0 + j];
    __syncthreads();
    for (int j = lane; j < deg; j += 64) {
        unsigned int my = (j < CAP) ? ld[wave][j] : rD[j0 + j];
        unsigned int m0 = my & 0xffffu, m1 = my >> 16;
        int c0 = 0, c1 = 0;
        for (int k = 0; k < deg; k++) {
            unsigned int p = (k < CAP) ? ld[wave][k] : rD[j0 + k];
            c0 += ((p & 0xffffu) == m0);
            c1 += ((p >> 16) == m1);
        }
        int e = eD[j0 + j];
        w0[e] = 1.0f / (float)c0;
        w1[e] = 1.0f / (float)c1;
    }
}

// root term: out[n,h] = x[n,:]@root[:,h] + b[h]   (fp32, full precision)
template <int FIN, int HOUT>
__global__ void k_base(const float* __restrict__ x0, const float* __restrict__ x1,
                       const float* __restrict__ x2,
                       const float* __restrict__ root, const float* __restrict__ bias,
                       float* o0, float* o1, float* o2) {
    const float* x = blockIdx.y == 0 ? x0 : (blockIdx.y == 1 ? x1 : x2);
    float* o = blockIdx.y == 0 ? o0 : (blockIdx.y == 1 ? o1 : o2);
    int lane = threadIdx.x % HOUT;
    int sub = threadIdx.x / HOUT;
    int n = blockIdx.x * (256 / HOUT) + sub;
    if (n >= NN) return;
    const float4* xr = (const float4*)(x + (size_t)n * FIN);
    float acc = bias[lane];
    #pragma unroll 4
    for (int f4 = 0; f4 < FIN / 4; f4++) {
        float4 xv = xr[f4];
        int f = f4 * 4;
        acc += xv.x * root[(f + 0) * HOUT + lane];
        acc += xv.y * root[(f + 1) * HOUT + lane];
        acc += xv.z * root[(f + 2) * HOUT + lane];
        acc += xv.w * root[(f + 3) * HOUT + lane];
    }
    o[(size_t)n * HOUT + lane] = acc;
}

// relation-grouped gather-GEMM with MFMA; epilogue writes weighted bf16 msg rows
// to dst-sorted slots (full-cacheline plain stores — no RMW atomics).
template <int FIN, int HOUT>
__launch_bounds__(256, (FIN == 128 ? 3 : 4))
__global__ void k_gemm(const unsigned short* __restrict__ X,
                       unsigned short* __restrict__ msg,
                       const int* __restrict__ perm, const int* __restrict__ off,
                       const int* __restrict__ toff, const int* __restrict__ t2r,
                       const float* __restrict__ w, const int* __restrict__ posD,
                       const unsigned short* __restrict__ WT,  // [R][HOUT][FIN] bf16
                       const int* __restrict__ ei) {
    int b = blockIdx.x;
    int r = t2r[b];
    if (r < 0) return;
    int t = b - toff[r];
    int ebase = off[r] + t * BM;
    int mcount = min(BM, off[r + 1] - ebase);

    constexpr int LDK = FIN + 8;  // +8 bf16 pad
    __shared__ unsigned short As[BM][LDK];
    __shared__ unsigned short Bs[HOUT][LDK];
    __shared__ int Sr[BM];
    __shared__ float Ww[BM];
    __shared__ int Pd[BM];

    int tid = threadIdx.x;
    if (tid < BM) {
        if (tid < mcount) {
            int e = perm[ebase + tid];
            Sr[tid] = ei[e];
            Ww[tid] = w[e];
            Pd[tid] = posD[e];
        } else { Sr[tid] = -1; Ww[tid] = 0.f; Pd[tid] = 0; }
    }
    __syncthreads();

    // stage B (W[r] transposed rows, 16B chunks)
    {
        const unsigned short* Wr = WT + (size_t)r * HOUT * FIN;
        constexpr int CHB = HOUT * FIN / 8;
        for (int c = tid; c < CHB; c += 256) {
            int row = c / (FIN / 8), cc = c % (FIN / 8);
            *(uint4*)&Bs[row][cc * 8] = *(const uint4*)&Wr[row * FIN + cc * 8];
        }
    }
    // stage A (gathered node rows)
    {
        constexpr int CHA = BM * FIN / 8;
        for (int c = tid; c < CHA; c += 256) {
            int row = c / (FIN / 8), cc = c % (FIN / 8);
            int s = Sr[row];
            uint4 v = {0u, 0u, 0u, 0u};
            if (s >= 0) v = *(const uint4*)&X[(size_t)s * FIN + cc * 8];
            *(uint4*)&As[row][cc * 8] = v;
        }
    }
    __syncthreads();

    const int wave = tid >> 6;      // 4 waves; each: 32 edges x HOUT
    const int lane = tid & 63;
    const int q = lane >> 4;
    const int ln = lane & 15;
    constexpr int NT = HOUT / 16;
    constexpr int KS = FIN / 32;
    const int mbase = wave * 32;

    floatx4 acc[2][NT];
    #pragma unroll
    for (int a = 0; a < 2; a++)
        #pragma unroll
        for (int nt = 0; nt < NT; nt++) acc[a][nt] = floatx4{0.f, 0.f, 0.f, 0.f};

    for (int ks = 0; ks < KS; ks++) {
        int kk = ks * 32 + q * 8;
        short8 af0 = *(const short8*)&As[mbase + ln][kk];
        short8 af1 = *(const short8*)&As[mbase + 16 + ln][kk];
        #pragma unroll
        for (int nt = 0; nt < NT; nt++) {
            short8 bf = *(const short8*)&Bs[nt * 16 + ln][kk];
            acc[0][nt] = __builtin_amdgcn_mfma_f32_16x16x32_bf16(af0, bf, acc[0][nt], 0, 0, 0);
            acc[1][nt] = __builtin_amdgcn_mfma_f32_16x16x32_bf16(af1, bf, acc[1][nt], 0, 0, 0);
        }
    }

    // epilogue: transpose weighted bf16 msgs through LDS (overlay As), then
    // coalesced full-line scatter to msg[posD[e]*HOUT .. +HOUT)
    __syncthreads();
    constexpr int LDM = HOUT + 8;   // pad to stagger banks; row stride %16B == 0
    unsigned short* Ms = &As[0][0];
    #pragma unroll
    for (int mt = 0; mt < 2; mt++) {
        #pragma unroll
        for (int rr2 = 0; rr2 < 4; rr2++) {
            int i = mbase + mt * 16 + q * 4 + rr2;
            float wt = Ww[i];
            #pragma unroll
            for (int nt = 0; nt < NT; nt++)
                Ms[i * LDM + nt * 16 + ln] = f2bf(wt * acc[mt][nt][rr2]);
        }
    }
    __syncthreads();
    constexpr int CH = HOUT / 8;    // 16B chunks per row
    for (int c = tid; c < BM * CH; c += 256) {
        int row = c / CH, cc = c % CH;
        if (row < mcount)
            *(uint4*)&msg[(size_t)Pd[row] * HOUT + cc * 8] = *(const uint4*)&Ms[row * LDM + cc * 8];
    }
}

// segment-sum msg rows per dst (contiguous in dst-sorted order), add root base,
// optional fused relu + bf16 cast. One wave per dst; 8B loads per lane.
template <int H, bool RELU>
__global__ void k_reduce(const unsigned short* __restrict__ msg,
                         const int* __restrict__ dstOff,
                         float* __restrict__ base_io,
                         unsigned short* __restrict__ bfout) {
    int d = blockIdx.x * 4 + (threadIdx.x >> 6);
    if (d >= NN) return;
    int lane = threadIdx.x & 63;
    constexpr int HC = H / 4;          // 8B chunks per row (H=64 -> 16, H=32 -> 8)
    constexpr int RPI = 64 / HC;       // rows per iteration
    int sub = lane / HC;
    int c4 = lane % HC;
    int j0 = dstOff[d], j1 = dstOff[d + 1];
    float a0 = 0.f, a1 = 0.f, a2 = 0.f, a3 = 0.f;
    for (int j = j0 + sub; j < j1; j += RPI) {
        uint2 v = *(const uint2*)&msg[(size_t)j * H + c4 * 4];
        a0 += bfbits2f(v.x << 16);
        a1 += bfbits2f(v.x & 0xffff0000u);
        a2 += bfbits2f(v.y << 16);
        a3 += bfbits2f(v.y & 0xffff0000u);
    }
    #pragma unroll
    for (int ofs = 32; ofs >= HC; ofs >>= 1) {
        a0 += __shfl_down(a0, ofs); a1 += __shfl_down(a1, ofs);
        a2 += __shfl_down(a2, ofs); a3 += __shfl_down(a3, ofs);
    }
    if (lane < HC) {
        size_t o = (size_t)d * H + c4 * 4;
        float v0 = base_io[o] + a0, v1 = base_io[o + 1] + a1;
        float v2 = base_io[o + 2] + a2, v3 = base_io[o + 3] + a3;
        if (RELU) {
            v0 = fmaxf(v0, 0.f); v1 = fmaxf(v1, 0.f);
            v2 = fmaxf(v2, 0.f); v3 = fmaxf(v3, 0.f);
        }
        base_io[o] = v0; base_io[o + 1] = v1; base_io[o + 2] = v2; base_io[o + 3] = v3;
        if (RELU) {
            bfout[o] = f2bf(v0); bfout[o + 1] = f2bf(v1);
            bfout[o + 2] = f2bf(v2); bfout[o + 3] = f2bf(v3);
        }
    }
}

// column sums of x2_o -> csum[32]
__global__ void k_mean(const float* __restrict__ x2o, float* csum) {
    __shared__ float s[256];
    int t = threadIdx.x; int hh = t & 31; int g = t >> 5;
    float acc = 0.f;
    for (int n = blockIdx.x * 8 + g; n < NN; n += gridDim.x * 8)
        acc += x2o[(size_t)n * 32 + hh];
    s[t] = acc;
    __syncthreads();
    if (t < 32) {
        float v = 0.f;
        for (int gg = 0; gg < 8; gg++) v += s[gg * 32 + t];
        unsafeAtomicAdd(&csum[t], v);
    }
}

// c = sigmoid(csum/N); v = disc_W @ c; bilinear scores
__global__ void k_disc(const float* __restrict__ x2o, const float* __restrict__ x2a,
                       const float* __restrict__ x2aa, const float* __restrict__ csum,
                       const float* __restrict__ discW, const float* __restrict__ discb,
                       float* ret_os, float* ret_osa) {
    __shared__ float c[32], v[32];
    int t = threadIdx.x;
    if (t < 32) c[t] = 1.f / (1.f + expf(-csum[t] * (1.f / NN)));
    __syncthreads();
    if (t < 32) {
        float a = 0.f;
        for (int j = 0; j < 32; j++) a += discW[t * 32 + j] * c[j];
        v[t] = a;
    }
    __syncthreads();
    float db = discb[0];
    int n = blockIdx.x * 256 + t;
    if (n < NN) {
        float s1 = 0.f, s2 = 0.f, s3 = 0.f;
        for (int j = 0; j < 32; j++) {
            float vj = v[j];
            s1 += x2o[(size_t)n * 32 + j] * vj;
            s2 += x2a[(size_t)n * 32 + j] * vj;
            s3 += x2aa[(size_t)n * 32 + j] * vj;
        }
        ret_os[n * 2] = s1 + db;  ret_os[n * 2 + 1] = s2 + db;
        ret_osa[n * 2] = s1 + db; ret_osa[n * 2 + 1] = s3 + db;
    }
}

// pair classifier: e(448) @ cls_W(448x65) + cls_b; 8 pairs per block staged in LDS
__global__ void k_cls(const float* __restrict__ h1o, const float* __restrict__ x2o,
                      const float* __restrict__ feat, const float* __restrict__ attt,
                      const int* __restrict__ idx, const float* __restrict__ clsW,
                      const float* __restrict__ clsb, float* __restrict__ log_out) {
    __shared__ float ev[8][448];
    int t = threadIdx.x;
    int b0 = blockIdx.x * 8;
    float a0 = attt[0], a1 = attt[1];
    for (int x = t; x < 8 * 448; x += 256) {
        int bb = x / 448, j = x % 448;
        int pair = b0 + bb;
        int hseg = j / 224;
        int jj = j % 224;
        int node = idx[hseg * BB + pair];
        float val;
        if (jj < 64) val = a0 * h1o[(size_t)node * 64 + jj];
        else if (jj < 96) val = a1 * x2o[(size_t)node * 32 + (jj - 64)];
        else val = feat[(size_t)node * 128 + (jj - 96)];
        ev[bb][j] = val;
    }
    __syncthreads();
    for (int o = t; o < 8 * RR; o += 256) {
        int bb = o / RR, r = o % RR;
        const float* e = ev[bb];
        float acc = clsb[r];
        #pragma unroll 8
        for (int f = 0; f < 448; f++) acc += e[f] * clsW[f * RR + r];
        log_out[(size_t)(b0 + bb) * RR + r] = acc;
    }
}

extern "C" void kernel_launch(void* const* d_in, const int* in_sizes, int n_in,
                              void* d_out, int out_size, void* d_ws, size_t ws_size,
                              hipStream_t stream) {
    const float* x_o   = (const float*)d_in[0];
    const float* x_a   = (const float*)d_in[1];
    const float* feat  = (const float*)d_in[2];
    const float* W1    = (const float*)d_in[3];
    const float* root1 = (const float*)d_in[4];
    const float* b1    = (const float*)d_in[5];
    const float* W2    = (const float*)d_in[6];
    const float* root2 = (const float*)d_in[7];
    const float* b2    = (const float*)d_in[8];
    const float* attt  = (const float*)d_in[9];
    const float* discW = (const float*)d_in[10];
    const float* discb = (const float*)d_in[11];
    const float* clsW  = (const float*)d_in[12];
    const float* clsb  = (const float*)d_in[13];
    const int* ei      = (const int*)d_in[14];
    const int* et0     = (const int*)d_in[15];
    const int* et1     = (const int*)d_in[16];
    const int* idx     = (const int*)d_in[17];

    char* ws = (char*)d_ws;
    float* csum = (float*)(ws + OFF_CSUM);
    int* cntD  = (int*)(ws + OFF_CNTD);
    int* bh0   = (int*)(ws + OFF_BH0);
    int* bh1   = (int*)(ws + OFF_BH1);
    int* bb0   = (int*)(ws + OFF_BB0);
    int* bb1   = (int*)(ws + OFF_BB1);
    int* dstOff = (int*)(ws + OFF_DSTOFF);
    int* off0  = (int*)(ws + OFF_OFF0);
    int* off1  = (int*)(ws + OFF_OFF1);
    int* toff0 = (int*)(ws + OFF_TOFF0);
    int* toff1 = (int*)(ws + OFF_TOFF1);
    int* t2r0  = (int*)(ws + OFF_T2R0);
    int* t2r1  = (int*)(ws + OFF_T2R1);
    int* slotE = (int*)(ws + OFF_SLOT);
    int* posD  = (int*)(ws + OFF_POSD);
    int* eD    = (int*)(ws + OFF_ED);
    unsigned int* rD = (unsigned int*)(ws + OFF_RD);
    unsigned short* xob = (unsigned short*)(ws + OFF_XOB);
    unsigned short* xab = (unsigned short*)(ws + OFF_XAB);
    float* w0 = (float*)(ws + OFF_W0);
    float* w1 = (float*)(ws + OFF_W1);
    int* perm0 = (int*)(ws + OFF_PERM0);
    int* perm1 = (int*)(ws + OFF_PERM1);
    float* h1o  = (float*)(ws + OFF_H1);
    float* h1a  = h1o + (size_t)NN * HH1;
    float* h1aa = h1a + (size_t)NN * HH1;
    unsigned short* h1bo  = (unsigned short*)(ws + OFF_H1B);
    unsigned short* h1ba  = h1bo + (size_t)NN * HH1;
    unsigned short* h1baa = h1ba + (size_t)NN * HH1;
    float* x2a  = (float*)(ws + OFF_X2A);
    float* x2aa = (float*)(ws + OFF_X2AA);
    unsigned short* w1t = (unsigned short*)(ws + OFF_W1BT);
    unsigned short* w2t = (unsigned short*)(ws + OFF_W2BT);
    unsigned short* msg = (unsigned short*)(ws + OFF_MSG);

    float* out = (float*)d_out;
    float* log_out = out + O_LOG;
    float* ret_os  = out + O_ROS;
    float* ret_osa = out + O_ROSA;
    float* x2o     = out + O_X2O;

    // 1) zero control block (csum + cntD) — ~80 KB only
    hipMemsetAsync(ws, 0, ZERO_BYTES, stream);

    // 2) preprocessing (no small-array global atomics anywhere)
    k_hist<<<NBH, 256, 0, stream>>>(et0, et1, bh0, bh1,
                                    x_o, x_a, W1, W2, xob, xab, w1t, w2t);
    k_scanR<<<1, 256, 0, stream>>>(bh0, bh1, bb0, bb1,
                                   off0, off1, toff0, toff1, t2r0, t2r1);
    k_fill<<<NBH, 256, 0, stream>>>(ei, et0, et1, off0, off1, bb0, bb1,
                                    perm0, perm1, cntD, slotE);
    k_scanD<<<1, 256, 0, stream>>>(cntD, dstOff);
    k_post<<<2500, 256, 0, stream>>>(ei, et0, et1, dstOff, slotE, posD, eD, rD);
    k_weights<<<NN / 4, 256, 0, stream>>>(dstOff, eD, rD, w0, w1);

    // 3) layer 1: base + per-encoding (edge GEMM -> dst reduce with fused relu/cvt)
    dim3 gb1(5000, 3);
    k_base<FIN1, HH1><<<gb1, 256, 0, stream>>>(x_o, x_a, x_o, root1, b1, h1o, h1a, h1aa);
    {
        const unsigned short* Xs[3] = {xob, xab, xob};
        float* Os[3] = {h1o, h1a, h1aa};
        unsigned short* Obs[3] = {h1bo, h1ba, h1baa};
        for (int enc = 0; enc < 3; enc++) {
            const int* perm = enc == 2 ? perm1 : perm0;
            const int* off  = enc == 2 ? off1 : off0;
            const int* toff = enc == 2 ? toff1 : toff0;
            const int* t2r  = enc == 2 ? t2r1 : t2r0;
            const float* w  = enc == 2 ? w1 : w0;
            k_gemm<FIN1, HH1><<<MAXT, 256, 0, stream>>>(Xs[enc], msg, perm, off, toff,
                                                        t2r, w, posD, w1t, ei);
            k_reduce<HH1, true><<<NN / 4, 256, 0, stream>>>(msg, dstOff, Os[enc], Obs[enc]);
        }
    }

    // 4) layer 2: base + per-encoding (edge GEMM -> dst reduce)
    dim3 gb2(2500, 3);
    k_base<HH1, HH2><<<gb2, 256, 0, stream>>>(h1o, h1a, h1aa, root2, b2, x2o, x2a, x2aa);
    {
        const unsigned short* Xs[3] = {h1bo, h1ba, h1baa};
        float* Os[3] = {x2o, x2a, x2aa};
        for (int enc = 0; enc < 3; enc++) {
            const int* perm = enc == 2 ? perm1 : perm0;
            const int* off  = enc == 2 ? off1 : off0;
            const int* toff = enc == 2 ? toff1 : toff0;
            const int* t2r  = enc == 2 ? t2r1 : t2r0;
            const float* w  = enc == 2 ? w1 : w0;
            k_gemm<HH1, HH2><<<MAXT, 256, 0, stream>>>(Xs[enc], msg, perm, off, toff,
                                                       t2r, w, posD, w2t, ei);
            k_reduce<HH2, false><<<NN / 4, 256, 0, stream>>>(msg, dstOff, Os[enc], nullptr);
        }
    }

    // 5) readout + discriminator + classifier
    k_mean<<<256, 256, 0, stream>>>(x2o, csum);
    k_disc<<<(NN + 255) / 256, 256, 0, stream>>>(x2o, x2a, x2aa, csum, discW, discb,
                                                 ret_os, ret_osa);
    k_cls<<<BB / 8, 256, 0, stream>>>(h1o, x2o, feat, attt, idx, clsW, clsb, log_out);
}

// Round 5
// 806.719 us; speedup vs baseline: 1.5467x; 1.1353x over previous
//
#include <hip/hip_runtime.h>
#include <hip/hip_bf16.h>

// ---------------- problem constants ----------------
#define NN 20000      // nodes
#define EE 640000     // edges
#define RR 65         // relations
#define FIN1 128      // input feat
#define HH1 64        // hidden1
#define HH2 32        // hidden2
#define BB 8192       // pairs

constexpr int BM = 128;                 // edge-tile rows per GEMM block
constexpr int MAXT = EE / BM + RR;      // 5065 upper bound on tiles per sort
constexpr int NBH = 256;                // histogram/placement blocks
constexpr int EPB = EE / NBH;           // 2500 edges per block
constexpr int NBT = (NN + BM - 1) / BM; // 157 node tiles

typedef __attribute__((ext_vector_type(8))) short short8;   // 8 bf16 (4 VGPRs) MFMA frag
typedef __attribute__((ext_vector_type(4))) float floatx4;  // 4 fp32 acc

// ---------------- workspace layout (bytes) ----------------
constexpr size_t aln(size_t x) { return (x + 255) & ~(size_t)255; }

constexpr size_t OFF_CSUM  = 0;                       // 32 float
constexpr size_t OFF_CNTD  = aln(OFF_CSUM + 32 * 4); // NN int (per-dst degree)
constexpr size_t ZERO_BYTES = OFF_CNTD + (size_t)NN * 4;   // memset [0, ZERO_BYTES)
constexpr size_t OFF_BH0   = aln(ZERO_BYTES);         // NBH*RR int block hists
constexpr size_t OFF_BH1   = OFF_BH0 + (size_t)NBH * RR * 4;
constexpr size_t OFF_BB0   = OFF_BH1 + (size_t)NBH * RR * 4;  // NBH*RR int block bases
constexpr size_t OFF_BB1   = OFF_BB0 + (size_t)NBH * RR * 4;
constexpr size_t OFF_DSTOFF = aln(OFF_BB1 + (size_t)NBH * RR * 4); // NN+1 int
constexpr size_t OFF_OFF0  = aln(OFF_DSTOFF + ((size_t)NN + 1) * 4); // 66 int
constexpr size_t OFF_OFF1  = OFF_OFF0 + 66 * 4;
constexpr size_t OFF_TOFF0 = OFF_OFF1 + 66 * 4;       // 66 int tile offsets
constexpr size_t OFF_TOFF1 = OFF_TOFF0 + 66 * 4;
constexpr size_t OFF_T2R0  = aln(OFF_TOFF1 + 66 * 4); // MAXT int tile->relation
constexpr size_t OFF_T2R1  = OFF_T2R0 + (size_t)MAXT * 4;
constexpr size_t OFF_SLOT  = aln(OFF_T2R1 + (size_t)MAXT * 4);  // E int (slot in dst seg)
constexpr size_t OFF_POSD  = OFF_SLOT + (size_t)EE * 4;         // E int (dst-sorted pos)
constexpr size_t OFF_ED    = OFF_POSD + (size_t)EE * 4;         // E int (pos -> edge)
constexpr size_t OFF_RD    = OFF_ED + (size_t)EE * 4;           // E uint (pos -> r0|r1<<16)
constexpr size_t OFF_XOB   = aln(OFF_RD + (size_t)EE * 4);      // N*F bf16
constexpr size_t OFF_XAB   = OFF_XOB + (size_t)NN * FIN1 * 2;
constexpr size_t OFF_W0    = aln(OFF_XAB + (size_t)NN * FIN1 * 2); // E float
constexpr size_t OFF_W1    = OFF_W0 + (size_t)EE * 4;
constexpr size_t OFF_PERM0 = OFF_W1 + (size_t)EE * 4;           // E int
constexpr size_t OFF_PERM1 = OFF_PERM0 + (size_t)EE * 4;
constexpr size_t OFF_H1    = OFF_PERM1 + (size_t)EE * 4;        // 3 * N*64 float
constexpr size_t OFF_H1B   = OFF_H1 + (size_t)3 * NN * HH1 * 4; // 3 * N*64 bf16
constexpr size_t OFF_X2A   = OFF_H1B + (size_t)3 * NN * HH1 * 2; // N*32 float
constexpr size_t OFF_X2AA  = OFF_X2A + (size_t)NN * HH2 * 4;
constexpr size_t OFF_W1BT  = OFF_X2AA + (size_t)NN * HH2 * 4;   // R*64*128 bf16 (transposed)
constexpr size_t OFF_W2BT  = OFF_W1BT + (size_t)RR * HH1 * FIN1 * 2; // R*32*64 bf16
constexpr size_t OFF_R1T   = OFF_W2BT + (size_t)RR * HH2 * HH1 * 2;  // 64*128 bf16
constexpr size_t OFF_R2T   = OFF_R1T + (size_t)HH1 * FIN1 * 2;       // 32*64 bf16
constexpr size_t OFF_MSG   = aln(OFF_R2T + (size_t)HH2 * HH1 * 2);   // E*64 bf16
constexpr size_t WS_END    = OFF_MSG + (size_t)EE * HH1 * 2;    // ~132 MB

// output offsets (floats)
constexpr size_t O_LOG  = 0;
constexpr size_t O_ROS  = (size_t)BB * RR;          // 532480
constexpr size_t O_ROSA = O_ROS + (size_t)NN * 2;   // 572480
constexpr size_t O_X2O  = O_ROSA + (size_t)NN * 2;  // 612480

__device__ inline unsigned short f2bf(float f) {
    __hip_bfloat16 h = __float2bfloat16(f);
    return *reinterpret_cast<unsigned short*>(&h);
}
__device__ inline float bfbits2f(unsigned int hi_bits) {   // bits already in [31:16]
    return __uint_as_float(hi_bits);
}

// ---------------- preprocessing ----------------
// per-block relation histograms via LDS, plain stores to blockHist (NO global
// atomics) + fused bf16 conversions (features, relation weights, root weights).
__global__ void k_hist(const int* __restrict__ et0, const int* __restrict__ et1,
                       int* __restrict__ bh0, int* __restrict__ bh1,
                       const float* __restrict__ x_o, const float* __restrict__ x_a,
                       const float* __restrict__ W1, const float* __restrict__ W2,
                       const float* __restrict__ root1, const float* __restrict__ root2,
                       unsigned short* xob, unsigned short* xab,
                       unsigned short* w1t, unsigned short* w2t,
                       unsigned short* r1t, unsigned short* r2t) {
    __shared__ int lh0[RR], lh1[RR];
    int t = threadIdx.x;
    if (t < RR) { lh0[t] = 0; lh1[t] = 0; }
    __syncthreads();
    int base = blockIdx.x * EPB;
    for (int i = t; i < EPB; i += 256) {
        atomicAdd(&lh0[et0[base + i]], 1);
        atomicAdd(&lh1[et1[base + i]], 1);
    }
    __syncthreads();
    if (t < RR) {
        bh0[blockIdx.x * RR + t] = lh0[t];
        bh1[blockIdx.x * RR + t] = lh1[t];
    }
    // streaming conversions (grid-stride over 256-block grid)
    int stride = gridDim.x * 256;
    int i0 = blockIdx.x * 256 + t;
    const int NX = NN * FIN1;
    for (int i = i0; i < NX; i += stride) { xob[i] = f2bf(x_o[i]); xab[i] = f2bf(x_a[i]); }
    const int NW1 = RR * HH1 * FIN1;
    for (int i = i0; i < NW1; i += stride) {
        int k = i % FIN1; int rh = i / FIN1; int hh = rh % HH1; int r = rh / HH1;
        w1t[i] = f2bf(W1[((size_t)r * FIN1 + k) * HH1 + hh]);
    }
    const int NW2 = RR * HH2 * HH1;
    for (int i = i0; i < NW2; i += stride) {
        int k = i % HH1; int rh = i / HH1; int hh = rh % HH2; int r = rh / HH2;
        w2t[i] = f2bf(W2[((size_t)r * HH1 + k) * HH2 + hh]);
    }
    const int NR1 = HH1 * FIN1;
    for (int i = i0; i < NR1; i += stride) {
        int k = i % FIN1; int hh = i / FIN1;
        r1t[i] = f2bf(root1[(size_t)k * HH1 + hh]);
    }
    const int NR2 = HH2 * HH1;
    for (int i = i0; i < NR2; i += stride) {
        int k = i % HH1; int hh = i / HH1;
        r2t[i] = f2bf(root2[(size_t)k * HH2 + hh]);
    }
}

// per-relation scan over blocks -> blockBase (within-relation exclusive prefix),
// then relation bucket offsets, tile offsets, tile->relation maps. Single block.
__global__ void k_scanR(const int* __restrict__ bh0, const int* __restrict__ bh1,
                        int* __restrict__ bb0, int* __restrict__ bb1,
                        int* off0, int* off1, int* toff0, int* toff1,
                        int* t2r0, int* t2r1) {
    __shared__ int h[2][RR];
    __shared__ int o[2][RR + 1], to[2][RR + 1];
    int t = threadIdx.x;
    if (t < 2 * RR) {
        int s = t / RR, r = t % RR;
        const int* bh = s ? bh1 : bh0;
        int* bb = s ? bb1 : bb0;
        int run = 0;
        for (int b = 0; b < NBH; b++) {
            int v = bh[b * RR + r];
            bb[b * RR + r] = run;
            run += v;
        }
        h[s][r] = run;
    }
    __syncthreads();
    if (t == 0) {
        for (int s = 0; s < 2; s++) {
            int a = 0, b = 0;
            for (int r = 0; r < RR; r++) {
                o[s][r] = a; to[s][r] = b;
                a += h[s][r]; b += (h[s][r] + BM - 1) / BM;
            }
            o[s][RR] = a; to[s][RR] = b;
        }
    }
    __syncthreads();
    if (t <= RR) { off0[t] = o[0][t]; off1[t] = o[1][t]; toff0[t] = to[0][t]; toff1[t] = to[1][t]; }
    for (int i = t; i < MAXT; i += blockDim.x) {
        for (int s = 0; s < 2; s++) {
            int total = to[s][RR];
            int r = -1;
            if (i < total) {
                int lo = 0, hi = RR;
                while (hi - lo > 1) { int mid = (lo + hi) >> 1; if (to[s][mid] <= i) lo = mid; else hi = mid; }
                r = lo;
            }
            (s ? t2r1 : t2r0)[i] = r;
        }
    }
}

// relation-sorted perm placement with deterministic bases (NO small-array global
// atomics). Only the benign 20k-address cntD scatter atomic remains.
__global__ void k_fill(const int* __restrict__ ei, const int* __restrict__ et0,
                       const int* __restrict__ et1,
                       const int* __restrict__ off0, const int* __restrict__ off1,
                       const int* __restrict__ bb0, const int* __restrict__ bb1,
                       int* perm0, int* perm1, int* cntD, int* slotE) {
    __shared__ int lc[2][RR];
    __shared__ int lb[2][RR];
    int t = threadIdx.x;
    if (t < RR) {
        lc[0][t] = 0; lc[1][t] = 0;
        lb[0][t] = off0[t] + bb0[blockIdx.x * RR + t];
        lb[1][t] = off1[t] + bb1[blockIdx.x * RR + t];
    }
    __syncthreads();
    int base = blockIdx.x * EPB;
    for (int i = t; i < EPB; i += 256) {
        int e = base + i;
        int r0 = et0[e], r1 = et1[e];
        int p0 = atomicAdd(&lc[0][r0], 1);
        int p1 = atomicAdd(&lc[1][r1], 1);
        perm0[lb[0][r0] + p0] = e;
        perm1[lb[1][r1] + p1] = e;
        slotE[e] = atomicAdd(&cntD[ei[EE + e]], 1);
    }
}

// exclusive scan of per-dst degrees -> dstOff[NN+1] (single block, 256 threads)
__global__ void k_scanD(const int* __restrict__ cntD, int* __restrict__ dstOff) {
    __shared__ int s[256];
    int t = threadIdx.x;
    constexpr int PER = (NN + 255) / 256;   // 79
    int lo = t * PER, hi = min(NN, lo + PER);
    int sum = 0;
    for (int i = lo; i < hi; i++) sum += cntD[i];
    s[t] = sum;
    __syncthreads();
    for (int ofs = 1; ofs < 256; ofs <<= 1) {
        int v = 0;
        if (t >= ofs) v = s[t - ofs];
        __syncthreads();
        if (t >= ofs) s[t] += v;
        __syncthreads();
    }
    int run = s[t] - sum;   // exclusive base
    for (int i = lo; i < hi; i++) { dstOff[i] = run; run += cntD[i]; }
    if (t == 255) dstOff[NN] = run;
}

// posD / inverse map / packed relations per dst-sorted slot
__global__ void k_post(const int* __restrict__ ei, const int* __restrict__ et0,
                       const int* __restrict__ et1, const int* __restrict__ dstOff,
                       const int* __restrict__ slotE,
                       int* posD, int* eD, unsigned int* rD) {
    int e = blockIdx.x * 256 + threadIdx.x;
    if (e < EE) {
        int d = ei[EE + e];
        int pos = dstOff[d] + slotE[e];
        posD[e] = pos;
        eD[pos] = e;
        rD[pos] = (unsigned)et0[e] | ((unsigned)et1[e] << 16);
    }
}

// per-(relation,dst) mean weights computed inside each dst segment (no atomics):
// w0[e] = 1 / #{e' in segment(dst): et0[e']==et0[e]}, same for w1.
__global__ void k_weights(const int* __restrict__ dstOff, const int* __restrict__ eD,
                          const unsigned int* __restrict__ rD,
                          float* __restrict__ w0, float* __restrict__ w1) {
    constexpr int CAP = 96;
    __shared__ unsigned int ld[4][CAP];
    int wave = threadIdx.x >> 6;
    int lane = threadIdx.x & 63;
    int d = blockIdx.x * 4 + wave;
    int j0 = 0, deg = 0;
    if (d < NN) { j0 = dstOff[d]; deg = dstOff[d + 1] - j0; }
    for (int j = lane; j < deg && j < CAP; j += 64) ld[wave][j] = rD[j0 + j];
    __syncthreads();
    for (int j = lane; j < deg; j += 64) {
        unsigned int my = (j < CAP) ? ld[wave][j] : rD[j0 + j];
        unsigned int m0 = my & 0xffffu, m1 = my >> 16;
        int c0 = 0, c1 = 0;
        for (int k = 0; k < deg; k++) {
            unsigned int p = (k < CAP) ? ld[wave][k] : rD[j0 + k];
            c0 += ((p & 0xffffu) == m0);
            c1 += ((p >> 16) == m1);
        }
        int e = eD[j0 + j];
        w0[e] = 1.0f / (float)c0;
        w1[e] = 1.0f / (float)c1;
    }
}

// root-term GEMM via MFMA: O[n,h] = Xb[n,:] @ rootT[h,:] + bias[h]  (fp32 out)
// Sequential 128-row tiles, bf16 inputs, fp32 accumulate; direct C-layout store.
template <int FIN, int HOUT>
__launch_bounds__(256, 3)
__global__ void k_bgemm(const unsigned short* __restrict__ X0,
                        const unsigned short* __restrict__ X1,
                        const unsigned short* __restrict__ X2,
                        const unsigned short* __restrict__ rootT,  // [HOUT][FIN] bf16
                        const float* __restrict__ bias,
                        float* O0, float* O1, float* O2) {
    const int enc = blockIdx.y;
    const unsigned short* X = enc == 0 ? X0 : enc == 1 ? X1 : X2;
    float* O = enc == 0 ? O0 : enc == 1 ? O1 : O2;
    int n0 = blockIdx.x * BM;
    int mcount = min(BM, NN - n0);

    constexpr int LDK = FIN + 8;
    __shared__ unsigned short As[BM][LDK];
    __shared__ unsigned short Bs[HOUT][LDK];

    int tid = threadIdx.x;
    // stage B (rootT rows)
    {
        constexpr int CHB = HOUT * FIN / 8;
        for (int c = tid; c < CHB; c += 256) {
            int row = c / (FIN / 8), cc = c % (FIN / 8);
            *(uint4*)&Bs[row][cc * 8] = *(const uint4*)&rootT[row * FIN + cc * 8];
        }
    }
    // stage A (sequential node rows)
    {
        constexpr int CHA = BM * FIN / 8;
        for (int c = tid; c < CHA; c += 256) {
            int row = c / (FIN / 8), cc = c % (FIN / 8);
            uint4 v = {0u, 0u, 0u, 0u};
            if (row < mcount) v = *(const uint4*)&X[(size_t)(n0 + row) * FIN + cc * 8];
            *(uint4*)&As[row][cc * 8] = v;
        }
    }
    __syncthreads();

    const int wave = tid >> 6;
    const int lane = tid & 63;
    const int q = lane >> 4;
    const int ln = lane & 15;
    constexpr int NT = HOUT / 16;
    constexpr int KS = FIN / 32;
    const int mbase = wave * 32;

    floatx4 acc[2][NT];
    #pragma unroll
    for (int a = 0; a < 2; a++)
        #pragma unroll
        for (int nt = 0; nt < NT; nt++) acc[a][nt] = floatx4{0.f, 0.f, 0.f, 0.f};

    for (int ks = 0; ks < KS; ks++) {
        int kk = ks * 32 + q * 8;
        short8 af0 = *(const short8*)&As[mbase + ln][kk];
        short8 af1 = *(const short8*)&As[mbase + 16 + ln][kk];
        #pragma unroll
        for (int nt = 0; nt < NT; nt++) {
            short8 bf = *(const short8*)&Bs[nt * 16 + ln][kk];
            acc[0][nt] = __builtin_amdgcn_mfma_f32_16x16x32_bf16(af0, bf, acc[0][nt], 0, 0, 0);
            acc[1][nt] = __builtin_amdgcn_mfma_f32_16x16x32_bf16(af1, bf, acc[1][nt], 0, 0, 0);
        }
    }

    // epilogue: direct store, n = mbase + mt*16 + q*4 + rr2, h = nt*16 + ln
    #pragma unroll
    for (int mt = 0; mt < 2; mt++) {
        #pragma unroll
        for (int rr2 = 0; rr2 < 4; rr2++) {
            int i = mbase + mt * 16 + q * 4 + rr2;
            int n = n0 + i;
            if (i < mcount) {
                #pragma unroll
                for (int nt = 0; nt < NT; nt++)
                    O[(size_t)n * HOUT + nt * 16 + ln] = acc[mt][nt][rr2] + bias[nt * 16 + ln];
            }
        }
    }
}

// relation-grouped gather-GEMM with MFMA; epilogue writes weighted bf16 msg rows
// to dst-sorted slots (full-cacheline plain stores — no RMW atomics).
template <int FIN, int HOUT>
__launch_bounds__(256, (FIN == 128 ? 3 : 4))
__global__ void k_gemm(const unsigned short* __restrict__ X,
                       unsigned short* __restrict__ msg,
                       const int* __restrict__ perm, const int* __restrict__ off,
                       const int* __restrict__ toff, const int* __restrict__ t2r,
                       const float* __restrict__ w, const int* __restrict__ posD,
                       const unsigned short* __restrict__ WT,  // [R][HOUT][FIN] bf16
                       const int* __restrict__ ei) {
    int b = blockIdx.x;
    int r = t2r[b];
    if (r < 0) return;
    int t = b - toff[r];
    int ebase = off[r] + t * BM;
    int mcount = min(BM, off[r + 1] - ebase);

    constexpr int LDK = FIN + 8;  // +8 bf16 pad
    __shared__ unsigned short As[BM][LDK];
    __shared__ unsigned short Bs[HOUT][LDK];
    __shared__ int Sr[BM];
    __shared__ float Ww[BM];
    __shared__ int Pd[BM];

    int tid = threadIdx.x;
    if (tid < BM) {
        if (tid < mcount) {
            int e = perm[ebase + tid];
            Sr[tid] = ei[e];
            Ww[tid] = w[e];
            Pd[tid] = posD[e];
        } else { Sr[tid] = -1; Ww[tid] = 0.f; Pd[tid] = 0; }
    }
    __syncthreads();

    // stage B (W[r] transposed rows, 16B chunks)
    {
        const unsigned short* Wr = WT + (size_t)r * HOUT * FIN;
        constexpr int CHB = HOUT * FIN / 8;
        for (int c = tid; c < CHB; c += 256) {
            int row = c / (FIN / 8), cc = c % (FIN / 8);
            *(uint4*)&Bs[row][cc * 8] = *(const uint4*)&Wr[row * FIN + cc * 8];
        }
    }
    // stage A (gathered node rows)
    {
        constexpr int CHA = BM * FIN / 8;
        for (int c = tid; c < CHA; c += 256) {
            int row = c / (FIN / 8), cc = c % (FIN / 8);
            int s = Sr[row];
            uint4 v = {0u, 0u, 0u, 0u};
            if (s >= 0) v = *(const uint4*)&X[(size_t)s * FIN + cc * 8];
            *(uint4*)&As[row][cc * 8] = v;
        }
    }
    __syncthreads();

    const int wave = tid >> 6;      // 4 waves; each: 32 edges x HOUT
    const int lane = tid & 63;
    const int q = lane >> 4;
    const int ln = lane & 15;
    constexpr int NT = HOUT / 16;
    constexpr int KS = FIN / 32;
    const int mbase = wave * 32;

    floatx4 acc[2][NT];
    #pragma unroll
    for (int a = 0; a < 2; a++)
        #pragma unroll
        for (int nt = 0; nt < NT; nt++) acc[a][nt] = floatx4{0.f, 0.f, 0.f, 0.f};

    for (int ks = 0; ks < KS; ks++) {
        int kk = ks * 32 + q * 8;
        short8 af0 = *(const short8*)&As[mbase + ln][kk];
        short8 af1 = *(const short8*)&As[mbase + 16 + ln][kk];
        #pragma unroll
        for (int nt = 0; nt < NT; nt++) {
            short8 bf = *(const short8*)&Bs[nt * 16 + ln][kk];
            acc[0][nt] = __builtin_amdgcn_mfma_f32_16x16x32_bf16(af0, bf, acc[0][nt], 0, 0, 0);
            acc[1][nt] = __builtin_amdgcn_mfma_f32_16x16x32_bf16(af1, bf, acc[1][nt], 0, 0, 0);
        }
    }

    // epilogue: transpose weighted bf16 msgs through LDS (overlay As), then
    // coalesced full-line scatter to msg[posD[e]*HOUT .. +HOUT)
    __syncthreads();
    constexpr int LDM = HOUT + 8;   // pad to stagger banks; row stride %16B == 0
    unsigned short* Ms = &As[0][0];
    #pragma unroll
    for (int mt = 0; mt < 2; mt++) {
        #pragma unroll
        for (int rr2 = 0; rr2 < 4; rr2++) {
            int i = mbase + mt * 16 + q * 4 + rr2;
            float wt = Ww[i];
            #pragma unroll
            for (int nt = 0; nt < NT; nt++)
                Ms[i * LDM + nt * 16 + ln] = f2bf(wt * acc[mt][nt][rr2]);
        }
    }
    __syncthreads();
    constexpr int CH = HOUT / 8;    // 16B chunks per row
    for (int c = tid; c < BM * CH; c += 256) {
        int row = c / CH, cc = c % CH;
        if (row < mcount)
            *(uint4*)&msg[(size_t)Pd[row] * HOUT + cc * 8] = *(const uint4*)&Ms[row * LDM + cc * 8];
    }
}

// segment-sum msg rows per dst (contiguous in dst-sorted order), add root base,
// optional fused relu + bf16 cast. One wave per dst; 8B loads per lane.
template <int H, bool RELU>
__global__ void k_reduce(const unsigned short* __restrict__ msg,
                         const int* __restrict__ dstOff,
                         float* __restrict__ base_io,
                         unsigned short* __restrict__ bfout) {
    int d = blockIdx.x * 4 + (threadIdx.x >> 6);
    if (d >= NN) return;
    int lane = threadIdx.x & 63;
    constexpr int HC = H / 4;          // 8B chunks per row (H=64 -> 16, H=32 -> 8)
    constexpr int RPI = 64 / HC;       // rows per iteration
    int sub = lane / HC;
    int c4 = lane % HC;
    int j0 = dstOff[d], j1 = dstOff[d + 1];
    float a0 = 0.f, a1 = 0.f, a2 = 0.f, a3 = 0.f;
    for (int j = j0 + sub; j < j1; j += RPI) {
        uint2 v = *(const uint2*)&msg[(size_t)j * H + c4 * 4];
        a0 += bfbits2f(v.x << 16);
        a1 += bfbits2f(v.x & 0xffff0000u);
        a2 += bfbits2f(v.y << 16);
        a3 += bfbits2f(v.y & 0xffff0000u);
    }
    #pragma unroll
    for (int ofs = 32; ofs >= HC; ofs >>= 1) {
        a0 += __shfl_down(a0, ofs); a1 += __shfl_down(a1, ofs);
        a2 += __shfl_down(a2, ofs); a3 += __shfl_down(a3, ofs);
    }
    if (lane < HC) {
        size_t o = (size_t)d * H + c4 * 4;
        float v0 = base_io[o] + a0, v1 = base_io[o + 1] + a1;
        float v2 = base_io[o + 2] + a2, v3 = base_io[o + 3] + a3;
        if (RELU) {
            v0 = fmaxf(v0, 0.f); v1 = fmaxf(v1, 0.f);
            v2 = fmaxf(v2, 0.f); v3 = fmaxf(v3, 0.f);
        }
        base_io[o] = v0; base_io[o + 1] = v1; base_io[o + 2] = v2; base_io[o + 3] = v3;
        if (RELU) {
            bfout[o] = f2bf(v0); bfout[o + 1] = f2bf(v1);
            bfout[o + 2] = f2bf(v2); bfout[o + 3] = f2bf(v3);
        }
    }
}

// column sums of x2_o -> csum[32]
__global__ void k_mean(const float* __restrict__ x2o, float* csum) {
    __shared__ float s[256];
    int t = threadIdx.x; int hh = t & 31; int g = t >> 5;
    float acc = 0.f;
    for (int n = blockIdx.x * 8 + g; n < NN; n += gridDim.x * 8)
        acc += x2o[(size_t)n * 32 + hh];
    s[t] = acc;
    __syncthreads();
    if (t < 32) {
        float v = 0.f;
        for (int gg = 0; gg < 8; gg++) v += s[gg * 32 + t];
        unsafeAtomicAdd(&csum[t], v);
    }
}

// c = sigmoid(csum/N); v = disc_W @ c; bilinear scores
__global__ void k_disc(const float* __restrict__ x2o, const float* __restrict__ x2a,
                       const float* __restrict__ x2aa, const float* __restrict__ csum,
                       const float* __restrict__ discW, const float* __restrict__ discb,
                       float* ret_os, float* ret_osa) {
    __shared__ float c[32], v[32];
    int t = threadIdx.x;
    if (t < 32) c[t] = 1.f / (1.f + expf(-csum[t] * (1.f / NN)));
    __syncthreads();
    if (t < 32) {
        float a = 0.f;
        for (int j = 0; j < 32; j++) a += discW[t * 32 + j] * c[j];
        v[t] = a;
    }
    __syncthreads();
    float db = discb[0];
    int n = blockIdx.x * 256 + t;
    if (n < NN) {
        float s1 = 0.f, s2 = 0.f, s3 = 0.f;
        for (int j = 0; j < 32; j++) {
            float vj = v[j];
            s1 += x2o[(size_t)n * 32 + j] * vj;
            s2 += x2a[(size_t)n * 32 + j] * vj;
            s3 += x2aa[(size_t)n * 32 + j] * vj;
        }
        ret_os[n * 2] = s1 + db;  ret_os[n * 2 + 1] = s2 + db;
        ret_osa[n * 2] = s1 + db; ret_osa[n * 2 + 1] = s3 + db;
    }
}

// pair classifier: e(448) @ cls_W(448x65) + cls_b; 8 pairs per block staged in LDS
__global__ void k_cls(const float* __restrict__ h1o, const float* __restrict__ x2o,
                      const float* __restrict__ feat, const float* __restrict__ attt,
                      const int* __restrict__ idx, const float* __restrict__ clsW,
                      const float* __restrict__ clsb, float* __restrict__ log_out) {
    __shared__ float ev[8][448];
    int t = threadIdx.x;
    int b0 = blockIdx.x * 8;
    float a0 = attt[0], a1 = attt[1];
    for (int x = t; x < 8 * 448; x += 256) {
        int bb = x / 448, j = x % 448;
        int pair = b0 + bb;
        int hseg = j / 224;
        int jj = j % 224;
        int node = idx[hseg * BB + pair];
        float val;
        if (jj < 64) val = a0 * h1o[(size_t)node * 64 + jj];
        else if (jj < 96) val = a1 * x2o[(size_t)node * 32 + (jj - 64)];
        else val = feat[(size_t)node * 128 + (jj - 96)];
        ev[bb][j] = val;
    }
    __syncthreads();
    for (int o = t; o < 8 * RR; o += 256) {
        int bb = o / RR, r = o % RR;
        const float* e = ev[bb];
        float acc = clsb[r];
        #pragma unroll 8
        for (int f = 0; f < 448; f++) acc += e[f] * clsW[f * RR + r];
        log_out[(size_t)(b0 + bb) * RR + r] = acc;
    }
}

extern "C" void kernel_launch(void* const* d_in, const int* in_sizes, int n_in,
                              void* d_out, int out_size, void* d_ws, size_t ws_size,
                              hipStream_t stream) {
    const float* x_o   = (const float*)d_in[0];
    const float* x_a   = (const float*)d_in[1];
    const float* feat  = (const float*)d_in[2];
    const float* W1    = (const float*)d_in[3];
    const float* root1 = (const float*)d_in[4];
    const float* b1    = (const float*)d_in[5];
    const float* W2    = (const float*)d_in[6];
    const float* root2 = (const float*)d_in[7];
    const float* b2    = (const float*)d_in[8];
    const float* attt  = (const float*)d_in[9];
    const float* discW = (const float*)d_in[10];
    const float* discb = (const float*)d_in[11];
    const float* clsW  = (const float*)d_in[12];
    const float* clsb  = (const float*)d_in[13];
    const int* ei      = (const int*)d_in[14];
    const int* et0     = (const int*)d_in[15];
    const int* et1     = (const int*)d_in[16];
    const int* idx     = (const int*)d_in[17];

    char* ws = (char*)d_ws;
    float* csum = (float*)(ws + OFF_CSUM);
    int* cntD  = (int*)(ws + OFF_CNTD);
    int* bh0   = (int*)(ws + OFF_BH0);
    int* bh1   = (int*)(ws + OFF_BH1);
    int* bb0   = (int*)(ws + OFF_BB0);
    int* bb1   = (int*)(ws + OFF_BB1);
    int* dstOff = (int*)(ws + OFF_DSTOFF);
    int* off0  = (int*)(ws + OFF_OFF0);
    int* off1  = (int*)(ws + OFF_OFF1);
    int* toff0 = (int*)(ws + OFF_TOFF0);
    int* toff1 = (int*)(ws + OFF_TOFF1);
    int* t2r0  = (int*)(ws + OFF_T2R0);
    int* t2r1  = (int*)(ws + OFF_T2R1);
    int* slotE = (int*)(ws + OFF_SLOT);
    int* posD  = (int*)(ws + OFF_POSD);
    int* eD    = (int*)(ws + OFF_ED);
    unsigned int* rD = (unsigned int*)(ws + OFF_RD);
    unsigned short* xob = (unsigned short*)(ws + OFF_XOB);
    unsigned short* xab = (unsigned short*)(ws + OFF_XAB);
    float* w0 = (float*)(ws + OFF_W0);
    float* w1 = (float*)(ws + OFF_W1);
    int* perm0 = (int*)(ws + OFF_PERM0);
    int* perm1 = (int*)(ws + OFF_PERM1);
    float* h1o  = (float*)(ws + OFF_H1);
    float* h1a  = h1o + (size_t)NN * HH1;
    float* h1aa = h1a + (size_t)NN * HH1;
    unsigned short* h1bo  = (unsigned short*)(ws + OFF_H1B);
    unsigned short* h1ba  = h1bo + (size_t)NN * HH1;
    unsigned short* h1baa = h1ba + (size_t)NN * HH1;
    float* x2a  = (float*)(ws + OFF_X2A);
    float* x2aa = (float*)(ws + OFF_X2AA);
    unsigned short* w1t = (unsigned short*)(ws + OFF_W1BT);
    unsigned short* w2t = (unsigned short*)(ws + OFF_W2BT);
    unsigned short* r1t = (unsigned short*)(ws + OFF_R1T);
    unsigned short* r2t = (unsigned short*)(ws + OFF_R2T);
    unsigned short* msg = (unsigned short*)(ws + OFF_MSG);

    float* out = (float*)d_out;
    float* log_out = out + O_LOG;
    float* ret_os  = out + O_ROS;
    float* ret_osa = out + O_ROSA;
    float* x2o     = out + O_X2O;

    // 1) zero control block (csum + cntD) — ~80 KB only
    hipMemsetAsync(ws, 0, ZERO_BYTES, stream);

    // 2) preprocessing (no small-array global atomics anywhere)
    k_hist<<<NBH, 256, 0, stream>>>(et0, et1, bh0, bh1,
                                    x_o, x_a, W1, W2, root1, root2,
                                    xob, xab, w1t, w2t, r1t, r2t);
    k_scanR<<<1, 256, 0, stream>>>(bh0, bh1, bb0, bb1,
                                   off0, off1, toff0, toff1, t2r0, t2r1);
    k_fill<<<NBH, 256, 0, stream>>>(ei, et0, et1, off0, off1, bb0, bb1,
                                    perm0, perm1, cntD, slotE);
    k_scanD<<<1, 256, 0, stream>>>(cntD, dstOff);
    k_post<<<2500, 256, 0, stream>>>(ei, et0, et1, dstOff, slotE, posD, eD, rD);
    k_weights<<<NN / 4, 256, 0, stream>>>(dstOff, eD, rD, w0, w1);

    // 3) layer 1: MFMA root GEMM + per-encoding (edge GEMM -> dst reduce + relu/cvt)
    {
        dim3 gb(NBT, 3);
        k_bgemm<FIN1, HH1><<<gb, 256, 0, stream>>>(xob, xab, xob, r1t, b1,
                                                   h1o, h1a, h1aa);
        const unsigned short* Xs[3] = {xob, xab, xob};
        float* Os[3] = {h1o, h1a, h1aa};
        unsigned short* Obs[3] = {h1bo, h1ba, h1baa};
        for (int enc = 0; enc < 3; enc++) {
            const int* perm = enc == 2 ? perm1 : perm0;
            const int* off  = enc == 2 ? off1 : off0;
            const int* toff = enc == 2 ? toff1 : toff0;
            const int* t2r  = enc == 2 ? t2r1 : t2r0;
            const float* w  = enc == 2 ? w1 : w0;
            k_gemm<FIN1, HH1><<<MAXT, 256, 0, stream>>>(Xs[enc], msg, perm, off, toff,
                                                        t2r, w, posD, w1t, ei);
            k_reduce<HH1, true><<<NN / 4, 256, 0, stream>>>(msg, dstOff, Os[enc], Obs[enc]);
        }
    }

    // 4) layer 2: MFMA root GEMM + per-encoding (edge GEMM -> dst reduce)
    {
        dim3 gb(NBT, 3);
        k_bgemm<HH1, HH2><<<gb, 256, 0, stream>>>(h1bo, h1ba, h1baa, r2t, b2,
                                                  x2o, x2a, x2aa);
        const unsigned short* Xs[3] = {h1bo, h1ba, h1baa};
        float* Os[3] = {x2o, x2a, x2aa};
        for (int enc = 0; enc < 3; enc++) {
            const int* perm = enc == 2 ? perm1 : perm0;
            const int* off  = enc == 2 ? off1 : off0;
            const int* toff = enc == 2 ? toff1 : toff0;
            const int* t2r  = enc == 2 ? t2r1 : t2r0;
            const float* w  = enc == 2 ? w1 : w0;
            k_gemm<HH1, HH2><<<MAXT, 256, 0, stream>>>(Xs[enc], msg, perm, off, toff,
                                                       t2r, w, posD, w2t, ei);
            k_reduce<HH2, false><<<NN / 4, 256, 0, stream>>>(msg, dstOff, Os[enc], nullptr);
        }
    }

    // 5) readout + discriminator + classifier
    k_mean<<<256, 256, 0, stream>>>(x2o, csum);
    k_disc<<<(NN + 255) / 256, 256, 0, stream>>>(x2o, x2a, x2aa, csum, discW, discb,
                                                 ret_os, ret_osa);
    k_cls<<<BB / 8, 256, 0, stream>>>(h1o, x2o, feat, attt, idx, clsW, clsb, log_out);
}

// Round 6
// 767.506 us; speedup vs baseline: 1.6257x; 1.0511x over previous
//
#include <hip/hip_runtime.h>
#include <hip/hip_bf16.h>

// ---------------- problem constants ----------------
#define NN 20000      // nodes
#define EE 640000     // edges
#define RR 65         // relations
#define FIN1 128      // input feat
#define HH1 64        // hidden1
#define HH2 32        // hidden2
#define BB 8192       // pairs

constexpr int BM = 128;                 // edge-tile rows per GEMM block
constexpr int MAXT = EE / BM + RR;      // 5065 upper bound on tiles per sort
constexpr int NBH = 256;                // histogram/placement blocks
constexpr int EPB = EE / NBH;           // 2500 edges per block
constexpr int NBT = (NN + BM - 1) / BM; // 157 node tiles

// classifier GEMM geometry (E[8192x448] @ clsW[448x65], padded)
constexpr int CLS_K  = 512;             // padded K (448 -> 512)
constexpr int CLS_N  = 80;              // padded N (65 -> 80)
constexpr int CLS_CK = 128;             // K chunk per stage
constexpr int CLS_BM = 64;              // pairs per block

typedef __attribute__((ext_vector_type(8))) short short8;   // 8 bf16 (4 VGPRs) MFMA frag
typedef __attribute__((ext_vector_type(4))) float floatx4;  // 4 fp32 acc

// ---------------- workspace layout (bytes) ----------------
constexpr size_t aln(size_t x) { return (x + 255) & ~(size_t)255; }

constexpr size_t OFF_CSUM  = 0;                       // 32 float
constexpr size_t OFF_CNTD  = aln(OFF_CSUM + 32 * 4); // NN int (per-dst degree)
constexpr size_t ZERO_BYTES = OFF_CNTD + (size_t)NN * 4;   // memset [0, ZERO_BYTES)
constexpr size_t OFF_BH0   = aln(ZERO_BYTES);         // NBH*RR int block hists
constexpr size_t OFF_BH1   = OFF_BH0 + (size_t)NBH * RR * 4;
constexpr size_t OFF_BB0   = OFF_BH1 + (size_t)NBH * RR * 4;  // NBH*RR int block bases
constexpr size_t OFF_BB1   = OFF_BB0 + (size_t)NBH * RR * 4;
constexpr size_t OFF_DSTOFF = aln(OFF_BB1 + (size_t)NBH * RR * 4); // NN+1 int
constexpr size_t OFF_OFF0  = aln(OFF_DSTOFF + ((size_t)NN + 1) * 4); // 66 int
constexpr size_t OFF_OFF1  = OFF_OFF0 + 66 * 4;
constexpr size_t OFF_TOFF0 = OFF_OFF1 + 66 * 4;       // 66 int tile offsets
constexpr size_t OFF_TOFF1 = OFF_TOFF0 + 66 * 4;
constexpr size_t OFF_T2R0  = aln(OFF_TOFF1 + 66 * 4); // MAXT int tile->relation
constexpr size_t OFF_T2R1  = OFF_T2R0 + (size_t)MAXT * 4;
constexpr size_t OFF_SLOT  = aln(OFF_T2R1 + (size_t)MAXT * 4);  // E int (slot in dst seg)
constexpr size_t OFF_POSD  = OFF_SLOT + (size_t)EE * 4;         // E int (dst-sorted pos)
constexpr size_t OFF_ED    = OFF_POSD + (size_t)EE * 4;         // E int (pos -> edge)
constexpr size_t OFF_RD    = OFF_ED + (size_t)EE * 4;           // E uint (pos -> r0|r1<<16)
constexpr size_t OFF_XOB   = aln(OFF_RD + (size_t)EE * 4);      // N*F bf16
constexpr size_t OFF_XAB   = OFF_XOB + (size_t)NN * FIN1 * 2;
constexpr size_t OFF_W0    = aln(OFF_XAB + (size_t)NN * FIN1 * 2); // E float
constexpr size_t OFF_W1    = OFF_W0 + (size_t)EE * 4;
constexpr size_t OFF_PERM0 = OFF_W1 + (size_t)EE * 4;           // E int
constexpr size_t OFF_PERM1 = OFF_PERM0 + (size_t)EE * 4;
constexpr size_t OFF_H1    = OFF_PERM1 + (size_t)EE * 4;        // 3 * N*64 float
constexpr size_t OFF_H1B   = OFF_H1 + (size_t)3 * NN * HH1 * 4; // 3 * N*64 bf16
constexpr size_t OFF_X2A   = OFF_H1B + (size_t)3 * NN * HH1 * 2; // N*32 float
constexpr size_t OFF_X2AA  = OFF_X2A + (size_t)NN * HH2 * 4;
constexpr size_t OFF_W1BT  = OFF_X2AA + (size_t)NN * HH2 * 4;   // R*64*128 bf16 (transposed)
constexpr size_t OFF_W2BT  = OFF_W1BT + (size_t)RR * HH1 * FIN1 * 2; // R*32*64 bf16
constexpr size_t OFF_R1T   = OFF_W2BT + (size_t)RR * HH2 * HH1 * 2;  // 64*128 bf16
constexpr size_t OFF_R2T   = OFF_R1T + (size_t)HH1 * FIN1 * 2;       // 32*64 bf16
constexpr size_t OFF_CWT   = OFF_R2T + (size_t)HH2 * HH1 * 2;        // 80*512 bf16 padded
constexpr size_t OFF_MSG   = aln(OFF_CWT + (size_t)CLS_N * CLS_K * 2); // E*64 bf16
constexpr size_t WS_END    = OFF_MSG + (size_t)EE * HH1 * 2;    // ~132 MB

// output offsets (floats)
constexpr size_t O_LOG  = 0;
constexpr size_t O_ROS  = (size_t)BB * RR;          // 532480
constexpr size_t O_ROSA = O_ROS + (size_t)NN * 2;   // 572480
constexpr size_t O_X2O  = O_ROSA + (size_t)NN * 2;  // 612480

__device__ inline unsigned short f2bf(float f) {
    __hip_bfloat16 h = __float2bfloat16(f);
    return *reinterpret_cast<unsigned short*>(&h);
}
__device__ inline float bfbits2f(unsigned int hi_bits) {   // bits already in [31:16]
    return __uint_as_float(hi_bits);
}

// ---------------- preprocessing ----------------
// per-block relation histograms via LDS, plain stores to blockHist (NO global
// atomics) + fused bf16 conversions (features, relation/root/classifier weights).
__global__ void k_hist(const int* __restrict__ et0, const int* __restrict__ et1,
                       int* __restrict__ bh0, int* __restrict__ bh1,
                       const float* __restrict__ x_o, const float* __restrict__ x_a,
                       const float* __restrict__ W1, const float* __restrict__ W2,
                       const float* __restrict__ root1, const float* __restrict__ root2,
                       const float* __restrict__ clsW,
                       unsigned short* xob, unsigned short* xab,
                       unsigned short* w1t, unsigned short* w2t,
                       unsigned short* r1t, unsigned short* r2t,
                       unsigned short* cwt) {
    __shared__ int lh0[RR], lh1[RR];
    int t = threadIdx.x;
    if (t < RR) { lh0[t] = 0; lh1[t] = 0; }
    __syncthreads();
    int base = blockIdx.x * EPB;
    for (int i = t; i < EPB; i += 256) {
        atomicAdd(&lh0[et0[base + i]], 1);
        atomicAdd(&lh1[et1[base + i]], 1);
    }
    __syncthreads();
    if (t < RR) {
        bh0[blockIdx.x * RR + t] = lh0[t];
        bh1[blockIdx.x * RR + t] = lh1[t];
    }
    // streaming conversions (grid-stride over 256-block grid)
    int stride = gridDim.x * 256;
    int i0 = blockIdx.x * 256 + t;
    const int NX = NN * FIN1;
    for (int i = i0; i < NX; i += stride) { xob[i] = f2bf(x_o[i]); xab[i] = f2bf(x_a[i]); }
    const int NW1 = RR * HH1 * FIN1;
    for (int i = i0; i < NW1; i += stride) {
        int k = i % FIN1; int rh = i / FIN1; int hh = rh % HH1; int r = rh / HH1;
        w1t[i] = f2bf(W1[((size_t)r * FIN1 + k) * HH1 + hh]);
    }
    const int NW2 = RR * HH2 * HH1;
    for (int i = i0; i < NW2; i += stride) {
        int k = i % HH1; int rh = i / HH1; int hh = rh % HH2; int r = rh / HH2;
        w2t[i] = f2bf(W2[((size_t)r * HH1 + k) * HH2 + hh]);
    }
    const int NR1 = HH1 * FIN1;
    for (int i = i0; i < NR1; i += stride) {
        int k = i % FIN1; int hh = i / FIN1;
        r1t[i] = f2bf(root1[(size_t)k * HH1 + hh]);
    }
    const int NR2 = HH2 * HH1;
    for (int i = i0; i < NR2; i += stride) {
        int k = i % HH1; int hh = i / HH1;
        r2t[i] = f2bf(root2[(size_t)k * HH2 + hh]);
    }
    const int NCW = CLS_N * CLS_K;   // padded transpose, zero-filled
    for (int i = i0; i < NCW; i += stride) {
        int k = i % CLS_K; int n = i / CLS_K;
        cwt[i] = (n < RR && k < 448) ? f2bf(clsW[(size_t)k * RR + n]) : (unsigned short)0;
    }
}

// per-relation scan over blocks -> blockBase (within-relation exclusive prefix),
// then relation bucket offsets, tile offsets, tile->relation maps. Single block.
__global__ void k_scanR(const int* __restrict__ bh0, const int* __restrict__ bh1,
                        int* __restrict__ bb0, int* __restrict__ bb1,
                        int* off0, int* off1, int* toff0, int* toff1,
                        int* t2r0, int* t2r1) {
    __shared__ int h[2][RR];
    __shared__ int o[2][RR + 1], to[2][RR + 1];
    int t = threadIdx.x;
    if (t < 2 * RR) {
        int s = t / RR, r = t % RR;
        const int* bh = s ? bh1 : bh0;
        int* bb = s ? bb1 : bb0;
        int run = 0;
        for (int b = 0; b < NBH; b++) {
            int v = bh[b * RR + r];
            bb[b * RR + r] = run;
            run += v;
        }
        h[s][r] = run;
    }
    __syncthreads();
    if (t == 0) {
        for (int s = 0; s < 2; s++) {
            int a = 0, b = 0;
            for (int r = 0; r < RR; r++) {
                o[s][r] = a; to[s][r] = b;
                a += h[s][r]; b += (h[s][r] + BM - 1) / BM;
            }
            o[s][RR] = a; to[s][RR] = b;
        }
    }
    __syncthreads();
    if (t <= RR) { off0[t] = o[0][t]; off1[t] = o[1][t]; toff0[t] = to[0][t]; toff1[t] = to[1][t]; }
    for (int i = t; i < MAXT; i += blockDim.x) {
        for (int s = 0; s < 2; s++) {
            int total = to[s][RR];
            int r = -1;
            if (i < total) {
                int lo = 0, hi = RR;
                while (hi - lo > 1) { int mid = (lo + hi) >> 1; if (to[s][mid] <= i) lo = mid; else hi = mid; }
                r = lo;
            }
            (s ? t2r1 : t2r0)[i] = r;
        }
    }
}

// relation-sorted perm placement with deterministic bases (NO small-array global
// atomics). Only the benign 20k-address cntD scatter atomic remains.
__global__ void k_fill(const int* __restrict__ ei, const int* __restrict__ et0,
                       const int* __restrict__ et1,
                       const int* __restrict__ off0, const int* __restrict__ off1,
                       const int* __restrict__ bb0, const int* __restrict__ bb1,
                       int* perm0, int* perm1, int* cntD, int* slotE) {
    __shared__ int lc[2][RR];
    __shared__ int lb[2][RR];
    int t = threadIdx.x;
    if (t < RR) {
        lc[0][t] = 0; lc[1][t] = 0;
        lb[0][t] = off0[t] + bb0[blockIdx.x * RR + t];
        lb[1][t] = off1[t] + bb1[blockIdx.x * RR + t];
    }
    __syncthreads();
    int base = blockIdx.x * EPB;
    for (int i = t; i < EPB; i += 256) {
        int e = base + i;
        int r0 = et0[e], r1 = et1[e];
        int p0 = atomicAdd(&lc[0][r0], 1);
        int p1 = atomicAdd(&lc[1][r1], 1);
        perm0[lb[0][r0] + p0] = e;
        perm1[lb[1][r1] + p1] = e;
        slotE[e] = atomicAdd(&cntD[ei[EE + e]], 1);
    }
}

// exclusive scan of per-dst degrees -> dstOff[NN+1] (single block, 256 threads)
__global__ void k_scanD(const int* __restrict__ cntD, int* __restrict__ dstOff) {
    __shared__ int s[256];
    int t = threadIdx.x;
    constexpr int PER = (NN + 255) / 256;   // 79
    int lo = t * PER, hi = min(NN, lo + PER);
    int sum = 0;
    for (int i = lo; i < hi; i++) sum += cntD[i];
    s[t] = sum;
    __syncthreads();
    for (int ofs = 1; ofs < 256; ofs <<= 1) {
        int v = 0;
        if (t >= ofs) v = s[t - ofs];
        __syncthreads();
        if (t >= ofs) s[t] += v;
        __syncthreads();
    }
    int run = s[t] - sum;   // exclusive base
    for (int i = lo; i < hi; i++) { dstOff[i] = run; run += cntD[i]; }
    if (t == 255) dstOff[NN] = run;
}

// posD / inverse map / packed relations per dst-sorted slot
__global__ void k_post(const int* __restrict__ ei, const int* __restrict__ et0,
                       const int* __restrict__ et1, const int* __restrict__ dstOff,
                       const int* __restrict__ slotE,
                       int* posD, int* eD, unsigned int* rD) {
    int e = blockIdx.x * 256 + threadIdx.x;
    if (e < EE) {
        int d = ei[EE + e];
        int pos = dstOff[d] + slotE[e];
        posD[e] = pos;
        eD[pos] = e;
        rD[pos] = (unsigned)et0[e] | ((unsigned)et1[e] << 16);
    }
}

// per-(relation,dst) mean weights computed inside each dst segment (no atomics):
// w0[e] = 1 / #{e' in segment(dst): et0[e']==et0[e]}, same for w1.
__global__ void k_weights(const int* __restrict__ dstOff, const int* __restrict__ eD,
                          const unsigned int* __restrict__ rD,
                          float* __restrict__ w0, float* __restrict__ w1) {
    constexpr int CAP = 96;
    __shared__ unsigned int ld[4][CAP];
    int wave = threadIdx.x >> 6;
    int lane = threadIdx.x & 63;
    int d = blockIdx.x * 4 + wave;
    int j0 = 0, deg = 0;
    if (d < NN) { j0 = dstOff[d]; deg = dstOff[d + 1] - j0; }
    for (int j = lane; j < deg && j < CAP; j += 64) ld[wave][j] = rD[j0 + j];
    __syncthreads();
    for (int j = lane; j < deg; j += 64) {
        unsigned int my = (j < CAP) ? ld[wave][j] : rD[j0 + j];
        unsigned int m0 = my & 0xffffu, m1 = my >> 16;
        int c0 = 0, c1 = 0;
        for (int k = 0; k < deg; k++) {
            unsigned int p = (k < CAP) ? ld[wave][k] : rD[j0 + k];
            c0 += ((p & 0xffffu) == m0);
            c1 += ((p >> 16) == m1);
        }
        int e = eD[j0 + j];
        w0[e] = 1.0f / (float)c0;
        w1[e] = 1.0f / (float)c1;
    }
}

// root-term GEMM via MFMA: O[n,h] = Xb[n,:] @ rootT[h,:] + bias[h]  (fp32 out)
template <int FIN, int HOUT>
__launch_bounds__(256, 3)
__global__ void k_bgemm(const unsigned short* __restrict__ X0,
                        const unsigned short* __restrict__ X1,
                        const unsigned short* __restrict__ X2,
                        const unsigned short* __restrict__ rootT,  // [HOUT][FIN] bf16
                        const float* __restrict__ bias,
                        float* O0, float* O1, float* O2) {
    const int enc = blockIdx.y;
    const unsigned short* X = enc == 0 ? X0 : enc == 1 ? X1 : X2;
    float* O = enc == 0 ? O0 : enc == 1 ? O1 : O2;
    int n0 = blockIdx.x * BM;
    int mcount = min(BM, NN - n0);

    constexpr int LDK = FIN + 8;
    __shared__ unsigned short As[BM][LDK];
    __shared__ unsigned short Bs[HOUT][LDK];

    int tid = threadIdx.x;
    {
        constexpr int CHB = HOUT * FIN / 8;
        for (int c = tid; c < CHB; c += 256) {
            int row = c / (FIN / 8), cc = c % (FIN / 8);
            *(uint4*)&Bs[row][cc * 8] = *(const uint4*)&rootT[row * FIN + cc * 8];
        }
    }
    {
        constexpr int CHA = BM * FIN / 8;
        for (int c = tid; c < CHA; c += 256) {
            int row = c / (FIN / 8), cc = c % (FIN / 8);
            uint4 v = {0u, 0u, 0u, 0u};
            if (row < mcount) v = *(const uint4*)&X[(size_t)(n0 + row) * FIN + cc * 8];
            *(uint4*)&As[row][cc * 8] = v;
        }
    }
    __syncthreads();

    const int wave = tid >> 6;
    const int lane = tid & 63;
    const int q = lane >> 4;
    const int ln = lane & 15;
    constexpr int NT = HOUT / 16;
    constexpr int KS = FIN / 32;
    const int mbase = wave * 32;

    floatx4 acc[2][NT];
    #pragma unroll
    for (int a = 0; a < 2; a++)
        #pragma unroll
        for (int nt = 0; nt < NT; nt++) acc[a][nt] = floatx4{0.f, 0.f, 0.f, 0.f};

    for (int ks = 0; ks < KS; ks++) {
        int kk = ks * 32 + q * 8;
        short8 af0 = *(const short8*)&As[mbase + ln][kk];
        short8 af1 = *(const short8*)&As[mbase + 16 + ln][kk];
        #pragma unroll
        for (int nt = 0; nt < NT; nt++) {
            short8 bf = *(const short8*)&Bs[nt * 16 + ln][kk];
            acc[0][nt] = __builtin_amdgcn_mfma_f32_16x16x32_bf16(af0, bf, acc[0][nt], 0, 0, 0);
            acc[1][nt] = __builtin_amdgcn_mfma_f32_16x16x32_bf16(af1, bf, acc[1][nt], 0, 0, 0);
        }
    }

    #pragma unroll
    for (int mt = 0; mt < 2; mt++) {
        #pragma unroll
        for (int rr2 = 0; rr2 < 4; rr2++) {
            int i = mbase + mt * 16 + q * 4 + rr2;
            int n = n0 + i;
            if (i < mcount) {
                #pragma unroll
                for (int nt = 0; nt < NT; nt++)
                    O[(size_t)n * HOUT + nt * 16 + ln] = acc[mt][nt][rr2] + bias[nt * 16 + ln];
            }
        }
    }
}

// relation-grouped gather-GEMM with MFMA; epilogue writes weighted bf16 msg rows
// to dst-sorted slots (full-cacheline plain stores — no RMW atomics).
template <int FIN, int HOUT>
__launch_bounds__(256, (FIN == 128 ? 3 : 4))
__global__ void k_gemm(const unsigned short* __restrict__ X,
                       unsigned short* __restrict__ msg,
                       const int* __restrict__ perm, const int* __restrict__ off,
                       const int* __restrict__ toff, const int* __restrict__ t2r,
                       const float* __restrict__ w, const int* __restrict__ posD,
                       const unsigned short* __restrict__ WT,  // [R][HOUT][FIN] bf16
                       const int* __restrict__ ei) {
    int b = blockIdx.x;
    int r = t2r[b];
    if (r < 0) return;
    int t = b - toff[r];
    int ebase = off[r] + t * BM;
    int mcount = min(BM, off[r + 1] - ebase);

    constexpr int LDK = FIN + 8;  // +8 bf16 pad
    __shared__ unsigned short As[BM][LDK];
    __shared__ unsigned short Bs[HOUT][LDK];
    __shared__ int Sr[BM];
    __shared__ float Ww[BM];
    __shared__ int Pd[BM];

    int tid = threadIdx.x;
    if (tid < BM) {
        if (tid < mcount) {
            int e = perm[ebase + tid];
            Sr[tid] = ei[e];
            Ww[tid] = w[e];
            Pd[tid] = posD[e];
        } else { Sr[tid] = -1; Ww[tid] = 0.f; Pd[tid] = 0; }
    }
    __syncthreads();

    // stage B (W[r] transposed rows, 16B chunks)
    {
        const unsigned short* Wr = WT + (size_t)r * HOUT * FIN;
        constexpr int CHB = HOUT * FIN / 8;
        for (int c = tid; c < CHB; c += 256) {
            int row = c / (FIN / 8), cc = c % (FIN / 8);
            *(uint4*)&Bs[row][cc * 8] = *(const uint4*)&Wr[row * FIN + cc * 8];
        }
    }
    // stage A (gathered node rows)
    {
        constexpr int CHA = BM * FIN / 8;
        for (int c = tid; c < CHA; c += 256) {
            int row = c / (FIN / 8), cc = c % (FIN / 8);
            int s = Sr[row];
            uint4 v = {0u, 0u, 0u, 0u};
            if (s >= 0) v = *(const uint4*)&X[(size_t)s * FIN + cc * 8];
            *(uint4*)&As[row][cc * 8] = v;
        }
    }
    __syncthreads();

    const int wave = tid >> 6;      // 4 waves; each: 32 edges x HOUT
    const int lane = tid & 63;
    const int q = lane >> 4;
    const int ln = lane & 15;
    constexpr int NT = HOUT / 16;
    constexpr int KS = FIN / 32;
    const int mbase = wave * 32;

    floatx4 acc[2][NT];
    #pragma unroll
    for (int a = 0; a < 2; a++)
        #pragma unroll
        for (int nt = 0; nt < NT; nt++) acc[a][nt] = floatx4{0.f, 0.f, 0.f, 0.f};

    for (int ks = 0; ks < KS; ks++) {
        int kk = ks * 32 + q * 8;
        short8 af0 = *(const short8*)&As[mbase + ln][kk];
        short8 af1 = *(const short8*)&As[mbase + 16 + ln][kk];
        #pragma unroll
        for (int nt = 0; nt < NT; nt++) {
            short8 bf = *(const short8*)&Bs[nt * 16 + ln][kk];
            acc[0][nt] = __builtin_amdgcn_mfma_f32_16x16x32_bf16(af0, bf, acc[0][nt], 0, 0, 0);
            acc[1][nt] = __builtin_amdgcn_mfma_f32_16x16x32_bf16(af1, bf, acc[1][nt], 0, 0, 0);
        }
    }

    // epilogue: transpose weighted bf16 msgs through LDS (overlay As), then
    // coalesced full-line scatter to msg[posD[e]*HOUT .. +HOUT)
    __syncthreads();
    constexpr int LDM = HOUT + 8;   // pad to stagger banks; row stride %16B == 0
    unsigned short* Ms = &As[0][0];
    #pragma unroll
    for (int mt = 0; mt < 2; mt++) {
        #pragma unroll
        for (int rr2 = 0; rr2 < 4; rr2++) {
            int i = mbase + mt * 16 + q * 4 + rr2;
            float wt = Ww[i];
            #pragma unroll
            for (int nt = 0; nt < NT; nt++)
                Ms[i * LDM + nt * 16 + ln] = f2bf(wt * acc[mt][nt][rr2]);
        }
    }
    __syncthreads();
    constexpr int CH = HOUT / 8;    // 16B chunks per row
    for (int c = tid; c < BM * CH; c += 256) {
        int row = c / CH, cc = c % CH;
        if (row < mcount)
            *(uint4*)&msg[(size_t)Pd[row] * HOUT + cc * 8] = *(const uint4*)&Ms[row * LDM + cc * 8];
    }
}

// segment-sum msg rows per dst (contiguous in dst-sorted order), add root base,
// optional fused relu + bf16 cast. One wave per dst; 8B loads per lane.
template <int H, bool RELU>
__global__ void k_reduce(const unsigned short* __restrict__ msg,
                         const int* __restrict__ dstOff,
                         float* __restrict__ base_io,
                         unsigned short* __restrict__ bfout) {
    int d = blockIdx.x * 4 + (threadIdx.x >> 6);
    if (d >= NN) return;
    int lane = threadIdx.x & 63;
    constexpr int HC = H / 4;          // 8B chunks per row (H=64 -> 16, H=32 -> 8)
    constexpr int RPI = 64 / HC;       // rows per iteration
    int sub = lane / HC;
    int c4 = lane % HC;
    int j0 = dstOff[d], j1 = dstOff[d + 1];
    float a0 = 0.f, a1 = 0.f, a2 = 0.f, a3 = 0.f;
    for (int j = j0 + sub; j < j1; j += RPI) {
        uint2 v = *(const uint2*)&msg[(size_t)j * H + c4 * 4];
        a0 += bfbits2f(v.x << 16);
        a1 += bfbits2f(v.x & 0xffff0000u);
        a2 += bfbits2f(v.y << 16);
        a3 += bfbits2f(v.y & 0xffff0000u);
    }
    #pragma unroll
    for (int ofs = 32; ofs >= HC; ofs >>= 1) {
        a0 += __shfl_down(a0, ofs); a1 += __shfl_down(a1, ofs);
        a2 += __shfl_down(a2, ofs); a3 += __shfl_down(a3, ofs);
    }
    if (lane < HC) {
        size_t o = (size_t)d * H + c4 * 4;
        float v0 = base_io[o] + a0, v1 = base_io[o + 1] + a1;
        float v2 = base_io[o + 2] + a2, v3 = base_io[o + 3] + a3;
        if (RELU) {
            v0 = fmaxf(v0, 0.f); v1 = fmaxf(v1, 0.f);
            v2 = fmaxf(v2, 0.f); v3 = fmaxf(v3, 0.f);
        }
        base_io[o] = v0; base_io[o + 1] = v1; base_io[o + 2] = v2; base_io[o + 3] = v3;
        if (RELU) {
            bfout[o] = f2bf(v0); bfout[o + 1] = f2bf(v1);
            bfout[o + 2] = f2bf(v2); bfout[o + 3] = f2bf(v3);
        }
    }
}

// column sums of x2_o -> csum[32]
__global__ void k_mean(const float* __restrict__ x2o, float* csum) {
    __shared__ float s[256];
    int t = threadIdx.x; int hh = t & 31; int g = t >> 5;
    float acc = 0.f;
    for (int n = blockIdx.x * 8 + g; n < NN; n += gridDim.x * 8)
        acc += x2o[(size_t)n * 32 + hh];
    s[t] = acc;
    __syncthreads();
    if (t < 32) {
        float v = 0.f;
        for (int gg = 0; gg < 8; gg++) v += s[gg * 32 + t];
        unsafeAtomicAdd(&csum[t], v);
    }
}

// c = sigmoid(csum/N); v = disc_W @ c; bilinear scores
__global__ void k_disc(const float* __restrict__ x2o, const float* __restrict__ x2a,
                       const float* __restrict__ x2aa, const float* __restrict__ csum,
                       const float* __restrict__ discW, const float* __restrict__ discb,
                       float* ret_os, float* ret_osa) {
    __shared__ float c[32], v[32];
    int t = threadIdx.x;
    if (t < 32) c[t] = 1.f / (1.f + expf(-csum[t] * (1.f / NN)));
    __syncthreads();
    if (t < 32) {
        float a = 0.f;
        for (int j = 0; j < 32; j++) a += discW[t * 32 + j] * c[j];
        v[t] = a;
    }
    __syncthreads();
    float db = discb[0];
    int n = blockIdx.x * 256 + t;
    if (n < NN) {
        float s1 = 0.f, s2 = 0.f, s3 = 0.f;
        for (int j = 0; j < 32; j++) {
            float vj = v[j];
            s1 += x2o[(size_t)n * 32 + j] * vj;
            s2 += x2a[(size_t)n * 32 + j] * vj;
            s3 += x2aa[(size_t)n * 32 + j] * vj;
        }
        ret_os[n * 2] = s1 + db;  ret_os[n * 2 + 1] = s2 + db;
        ret_osa[n * 2] = s1 + db; ret_osa[n * 2 + 1] = s3 + db;
    }
}

// pair classifier as MFMA GEMM: logit[p, r] = E[p, :448] @ clsW[:448, r] + clsb[r]
// E rows gathered on the fly into LDS as bf16, K padded to 512, N padded to 80.
__launch_bounds__(256, 2)
__global__ void k_clsg(const float* __restrict__ h1o, const float* __restrict__ x2o,
                       const float* __restrict__ feat, const float* __restrict__ attt,
                       const int* __restrict__ idx,
                       const unsigned short* __restrict__ cwt,  // [80][512] bf16 padded
                       const float* __restrict__ clsb, float* __restrict__ log_out) {
    constexpr int LDK = CLS_CK + 8;
    __shared__ unsigned short As[CLS_BM][LDK];
    __shared__ unsigned short Bs[CLS_N][LDK];
    __shared__ int nd[2][CLS_BM];

    int tid = threadIdx.x;
    int p0 = blockIdx.x * CLS_BM;
    if (tid < CLS_BM) {
        nd[0][tid] = idx[p0 + tid];
        nd[1][tid] = idx[BB + p0 + tid];
    }
    float a0 = attt[0], a1 = attt[1];

    const int wave = tid >> 6;
    const int lane = tid & 63;
    const int q = lane >> 4;
    const int ln = lane & 15;
    constexpr int NT = CLS_N / 16;   // 5
    const int mbase = wave * 16;

    floatx4 acc[NT];
    #pragma unroll
    for (int nt = 0; nt < NT; nt++) acc[nt] = floatx4{0.f, 0.f, 0.f, 0.f};

    for (int ch = 0; ch < CLS_K / CLS_CK; ch++) {
        int kbase = ch * CLS_CK;
        __syncthreads();   // protect LDS reuse across chunks (and nd on first pass)
        // stage B chunk (16B vector loads)
        for (int c = tid; c < CLS_N * CLS_CK / 8; c += 256) {
            int row = c / (CLS_CK / 8), cc = c % (CLS_CK / 8);
            *(uint4*)&Bs[row][cc * 8] = *(const uint4*)&cwt[(size_t)row * CLS_K + kbase + cc * 8];
        }
        // stage A chunk: gather E values, float4 granularity (segments 4-aligned)
        for (int c = tid; c < CLS_BM * CLS_CK / 4; c += 256) {
            int row = c / (CLS_CK / 4);
            int j4 = (c % (CLS_CK / 4)) * 4;
            int j = kbase + j4;
            float4 v = {0.f, 0.f, 0.f, 0.f};
            if (j < 448) {
                int hseg = j / 224, jj = j % 224;
                int node = nd[hseg][row];
                if (jj < 64) {
                    v = *(const float4*)&h1o[(size_t)node * 64 + jj];
                    v.x *= a0; v.y *= a0; v.z *= a0; v.w *= a0;
                } else if (jj < 96) {
                    v = *(const float4*)&x2o[(size_t)node * 32 + (jj - 64)];
                    v.x *= a1; v.y *= a1; v.z *= a1; v.w *= a1;
                } else {
                    v = *(const float4*)&feat[(size_t)node * 128 + (jj - 96)];
                }
            }
            uint2 pk;
            pk.x = (unsigned)f2bf(v.x) | ((unsigned)f2bf(v.y) << 16);
            pk.y = (unsigned)f2bf(v.z) | ((unsigned)f2bf(v.w) << 16);
            *(uint2*)&As[row][j4] = pk;
        }
        __syncthreads();
        // MFMA over the chunk
        #pragma unroll
        for (int ks = 0; ks < CLS_CK / 32; ks++) {
            int kk = ks * 32 + q * 8;
            short8 af = *(const short8*)&As[mbase + ln][kk];
            #pragma unroll
            for (int nt = 0; nt < NT; nt++) {
                short8 bf = *(const short8*)&Bs[nt * 16 + ln][kk];
                acc[nt] = __builtin_amdgcn_mfma_f32_16x16x32_bf16(af, bf, acc[nt], 0, 0, 0);
            }
        }
    }

    // epilogue: C/D layout col=ln, row=q*4+rr2
    #pragma unroll
    for (int rr2 = 0; rr2 < 4; rr2++) {
        int i = mbase + q * 4 + rr2;
        int pair = p0 + i;
        #pragma unroll
        for (int nt = 0; nt < NT; nt++) {
            int col = nt * 16 + ln;
            if (col < RR)
                log_out[(size_t)pair * RR + col] = acc[nt][rr2] + clsb[col];
        }
    }
}

extern "C" void kernel_launch(void* const* d_in, const int* in_sizes, int n_in,
                              void* d_out, int out_size, void* d_ws, size_t ws_size,
                              hipStream_t stream) {
    const float* x_o   = (const float*)d_in[0];
    const float* x_a   = (const float*)d_in[1];
    const float* feat  = (const float*)d_in[2];
    const float* W1    = (const float*)d_in[3];
    const float* root1 = (const float*)d_in[4];
    const float* b1    = (const float*)d_in[5];
    const float* W2    = (const float*)d_in[6];
    const float* root2 = (const float*)d_in[7];
    const float* b2    = (const float*)d_in[8];
    const float* attt  = (const float*)d_in[9];
    const float* discW = (const float*)d_in[10];
    const float* discb = (const float*)d_in[11];
    const float* clsW  = (const float*)d_in[12];
    const float* clsb  = (const float*)d_in[13];
    const int* ei      = (const int*)d_in[14];
    const int* et0     = (const int*)d_in[15];
    const int* et1     = (const int*)d_in[16];
    const int* idx     = (const int*)d_in[17];

    char* ws = (char*)d_ws;
    float* csum = (float*)(ws + OFF_CSUM);
    int* cntD  = (int*)(ws + OFF_CNTD);
    int* bh0   = (int*)(ws + OFF_BH0);
    int* bh1   = (int*)(ws + OFF_BH1);
    int* bb0   = (int*)(ws + OFF_BB0);
    int* bb1   = (int*)(ws + OFF_BB1);
    int* dstOff = (int*)(ws + OFF_DSTOFF);
    int* off0  = (int*)(ws + OFF_OFF0);
    int* off1  = (int*)(ws + OFF_OFF1);
    int* toff0 = (int*)(ws + OFF_TOFF0);
    int* toff1 = (int*)(ws + OFF_TOFF1);
    int* t2r0  = (int*)(ws + OFF_T2R0);
    int* t2r1  = (int*)(ws + OFF_T2R1);
    int* slotE = (int*)(ws + OFF_SLOT);
    int* posD  = (int*)(ws + OFF_POSD);
    int* eD    = (int*)(ws + OFF_ED);
    unsigned int* rD = (unsigned int*)(ws + OFF_RD);
    unsigned short* xob = (unsigned short*)(ws + OFF_XOB);
    unsigned short* xab = (unsigned short*)(ws + OFF_XAB);
    float* w0 = (float*)(ws + OFF_W0);
    float* w1 = (float*)(ws + OFF_W1);
    int* perm0 = (int*)(ws + OFF_PERM0);
    int* perm1 = (int*)(ws + OFF_PERM1);
    float* h1o  = (float*)(ws + OFF_H1);
    float* h1a  = h1o + (size_t)NN * HH1;
    float* h1aa = h1a + (size_t)NN * HH1;
    unsigned short* h1bo  = (unsigned short*)(ws + OFF_H1B);
    unsigned short* h1ba  = h1bo + (size_t)NN * HH1;
    unsigned short* h1baa = h1ba + (size_t)NN * HH1;
    float* x2a  = (float*)(ws + OFF_X2A);
    float* x2aa = (float*)(ws + OFF_X2AA);
    unsigned short* w1t = (unsigned short*)(ws + OFF_W1BT);
    unsigned short* w2t = (unsigned short*)(ws + OFF_W2BT);
    unsigned short* r1t = (unsigned short*)(ws + OFF_R1T);
    unsigned short* r2t = (unsigned short*)(ws + OFF_R2T);
    unsigned short* cwt = (unsigned short*)(ws + OFF_CWT);
    unsigned short* msg = (unsigned short*)(ws + OFF_MSG);

    float* out = (float*)d_out;
    float* log_out = out + O_LOG;
    float* ret_os  = out + O_ROS;
    float* ret_osa = out + O_ROSA;
    float* x2o     = out + O_X2O;

    // 1) zero control block (csum + cntD) — ~80 KB only
    hipMemsetAsync(ws, 0, ZERO_BYTES, stream);

    // 2) preprocessing (no small-array global atomics anywhere)
    k_hist<<<NBH, 256, 0, stream>>>(et0, et1, bh0, bh1,
                                    x_o, x_a, W1, W2, root1, root2, clsW,
                                    xob, xab, w1t, w2t, r1t, r2t, cwt);
    k_scanR<<<1, 256, 0, stream>>>(bh0, bh1, bb0, bb1,
                                   off0, off1, toff0, toff1, t2r0, t2r1);
    k_fill<<<NBH, 256, 0, stream>>>(ei, et0, et1, off0, off1, bb0, bb1,
                                    perm0, perm1, cntD, slotE);
    k_scanD<<<1, 256, 0, stream>>>(cntD, dstOff);
    k_post<<<2500, 256, 0, stream>>>(ei, et0, et1, dstOff, slotE, posD, eD, rD);
    k_weights<<<NN / 4, 256, 0, stream>>>(dstOff, eD, rD, w0, w1);

    // 3) layer 1: MFMA root GEMM + per-encoding (edge GEMM -> dst reduce + relu/cvt)
    {
        dim3 gb(NBT, 3);
        k_bgemm<FIN1, HH1><<<gb, 256, 0, stream>>>(xob, xab, xob, r1t, b1,
                                                   h1o, h1a, h1aa);
        const unsigned short* Xs[3] = {xob, xab, xob};
        float* Os[3] = {h1o, h1a, h1aa};
        unsigned short* Obs[3] = {h1bo, h1ba, h1baa};
        for (int enc = 0; enc < 3; enc++) {
            const int* perm = enc == 2 ? perm1 : perm0;
            const int* off  = enc == 2 ? off1 : off0;
            const int* toff = enc == 2 ? toff1 : toff0;
            const int* t2r  = enc == 2 ? t2r1 : t2r0;
            const float* w  = enc == 2 ? w1 : w0;
            k_gemm<FIN1, HH1><<<MAXT, 256, 0, stream>>>(Xs[enc], msg, perm, off, toff,
                                                        t2r, w, posD, w1t, ei);
            k_reduce<HH1, true><<<NN / 4, 256, 0, stream>>>(msg, dstOff, Os[enc], Obs[enc]);
        }
    }

    // 4) layer 2: MFMA root GEMM + per-encoding (edge GEMM -> dst reduce)
    {
        dim3 gb(NBT, 3);
        k_bgemm<HH1, HH2><<<gb, 256, 0, stream>>>(h1bo, h1ba, h1baa, r2t, b2,
                                                  x2o, x2a, x2aa);
        const unsigned short* Xs[3] = {h1bo, h1ba, h1baa};
        float* Os[3] = {x2o, x2a, x2aa};
        for (int enc = 0; enc < 3; enc++) {
            const int* perm = enc == 2 ? perm1 : perm0;
            const int* off  = enc == 2 ? off1 : off0;
            const int* toff = enc == 2 ? toff1 : toff0;
            const int* t2r  = enc == 2 ? t2r1 : t2r0;
            const float* w  = enc == 2 ? w1 : w0;
            k_gemm<HH1, HH2><<<MAXT, 256, 0, stream>>>(Xs[enc], msg, perm, off, toff,
                                                       t2r, w, posD, w2t, ei);
            k_reduce<HH2, false><<<NN / 4, 256, 0, stream>>>(msg, dstOff, Os[enc], nullptr);
        }
    }

    // 5) readout + discriminator + classifier (MFMA)
    k_mean<<<256, 256, 0, stream>>>(x2o, csum);
    k_disc<<<(NN + 255) / 256, 256, 0, stream>>>(x2o, x2a, x2aa, csum, discW, discb,
                                                 ret_os, ret_osa);
    k_clsg<<<BB / CLS_BM, 256, 0, stream>>>(h1o, x2o, feat, attt, idx, cwt, clsb, log_out);
}